// Round 1
// baseline (341.789 us; speedup 1.0000x reference)
//
#include <hip/hip_runtime.h>
#include <hip/hip_bf16.h>
#include <hip/hip_cooperative_groups.h>
#include <cstdint>

namespace cg = cooperative_groups;

// Problem constants
#define NB   32      // batch
#define NC   256     // z channels
#define NE   128     // embed dim
#define NS   256     // H*W pixels per batch
#define NV   4096    // vocab
#define NP   8192    // total pixels
#define NSPLIT 8     // vocab splits (512 codes each)

typedef unsigned short ushort_t;
typedef __attribute__((ext_vector_type(8))) short bf16x8;
typedef __attribute__((ext_vector_type(8))) unsigned short us8;
typedef __attribute__((ext_vector_type(4))) float f32x4;

__device__ __forceinline__ float bf2f(ushort_t u) {
    union { unsigned int i; float f; } x; x.i = ((unsigned int)u) << 16; return x.f;
}
__device__ __forceinline__ ushort_t f2bf(float f) {
    __hip_bfloat16 h = __float2bfloat16(f);
    ushort_t u; __builtin_memcpy(&u, &h, 2); return u;
}
__device__ __forceinline__ unsigned asu(float f) { unsigned u; __builtin_memcpy(&u,&f,4); return u; }
__device__ __forceinline__ float    asf(unsigned u) { float f; __builtin_memcpy(&f,&u,4); return f; }

// ---------------------------------------------------------------------------
// Fused single-launch pipeline (cooperative). Phase bodies are byte-identical
// math to the validated 4-kernel version; only the work distribution changed
// (grid-stride over the old blockIdx space + grid.sync() between phases).
// LDS arena = 40960 B (max of the four phases), aliased per phase.
// ---------------------------------------------------------------------------
__global__ __launch_bounds__(256, 3) void vq_fused(
    const float* __restrict__ z_e, const float* __restrict__ pre_w,
    const float* __restrict__ pre_b, const float* __restrict__ emb,
    const float* __restrict__ post_w, const float* __restrict__ post_b,
    float* __restrict__ out_z, float* __restrict__ out_zq,
    float* __restrict__ out_rec, ushort_t* __restrict__ Bpack,
    float* __restrict__ cnorm, int* __restrict__ pidx4)
{
    cg::grid_group grid = cg::this_grid();
    __shared__ __align__(16) char smraw[40960];
    const int t = threadIdx.x;

    // ===================== Phase A: pre_conv (u<1024) + pack (u>=1024) =====
    for (int u = blockIdx.x; u < 1152; u += gridDim.x) {
        if (u >= 1024) {   // ---- pack role: 128 units x 32 codes
            const int pu    = u - 1024;
            const int v     = pu * 32 + (t >> 3);
            const int chunk = t & 7;
            const float4* rp = (const float4*)(emb + (size_t)v * NE + chunk * 16);
            float4 x0 = rp[0], x1 = rp[1], x2 = rp[2], x3 = rp[3];
            float xs[16] = { x0.x, x0.y, x0.z, x0.w, x1.x, x1.y, x1.z, x1.w,
                             x2.x, x2.y, x2.z, x2.w, x3.x, x3.y, x3.z, x3.w };
            us8 h0, h1;
            float nn = 0.f;
#pragma unroll
            for (int j = 0; j < 8; j++) {
                nn = fmaf(xs[j], xs[j], nn);
                h0[j] = f2bf(xs[j]);
            }
#pragma unroll
            for (int j = 0; j < 8; j++) {
                nn = fmaf(xs[8 + j], xs[8 + j], nn);
                h1[j] = f2bf(xs[8 + j]);
            }
            nn += __shfl_xor(nn, 1);
            nn += __shfl_xor(nn, 2);
            nn += __shfl_xor(nn, 4);
            if (chunk == 0) cnorm[v] = 0.5f * nn;

            const int G  = v >> 4;
            const int ks = chunk >> 1;
            const int q0 = (chunk & 1) * 2;
            const int L0 = (v & 15) | (q0 << 4);
            const int L1 = (v & 15) | ((q0 + 1) << 4);
            *(us8*)(Bpack + ((size_t)G * 4 + ks) * 512 + L0 * 8) = h0;
            *(us8*)(Bpack + ((size_t)G * 4 + ks) * 512 + L1 * 8) = h1;
            continue;
        }

        // ---- pre_conv role
        float* wtile = (float*)smraw;            // 16 KB
        float* part  = (float*)(smraw + 16384);  // 16 KB
        const int e0 = (u >> 7) * 16;
        const int b  = (u >> 2) & 31;
        const int s0 = (u & 3) * 64;

        __syncthreads();   // LDS-reuse guard across strided units
        for (int idx = t; idx < 16 * 256; idx += 256)
            wtile[idx] = pre_w[(e0 + (idx >> 8)) * 256 + (idx & 255)];
        __syncthreads();

        const int kq = t >> 6, sl = t & 63;
        float acc[16];
#pragma unroll
        for (int r = 0; r < 16; r++) acc[r] = 0.f;

        const float* zin = z_e + (size_t)(b * NC + kq * 64) * NS + s0 + sl;
        const int cb = kq * 64;
#pragma unroll 4
        for (int i = 0; i < 16; i++) {
            const int c = i * 4;
            float z0 = zin[(c + 0) * NS];
            float z1 = zin[(c + 1) * NS];
            float z2 = zin[(c + 2) * NS];
            float z3 = zin[(c + 3) * NS];
#pragma unroll
            for (int r = 0; r < 16; r++) {
                float4 w = *(const float4*)&wtile[r * 256 + cb + c];
                acc[r] = fmaf(z0, w.x, fmaf(z1, w.y, fmaf(z2, w.z, fmaf(z3, w.w, acc[r]))));
            }
        }
#pragma unroll
        for (int r = 0; r < 16; r++)
            part[(kq * 16 + r) * 64 + sl] = acc[r];
        __syncthreads();

        const int r4 = t >> 6, sl2 = t & 63;
#pragma unroll
        for (int j = 0; j < 4; j++) {
            const int r = j * 4 + r4;
            float v = pre_b[e0 + r]
                    + part[(0 * 16 + r) * 64 + sl2]
                    + part[(1 * 16 + r) * 64 + sl2]
                    + part[(2 * 16 + r) * 64 + sl2]
                    + part[(3 * 16 + r) * 64 + sl2];
            out_z[(size_t)(b * NE + e0 + r) * NS + s0 + sl2] = v;
        }
    }
    grid.sync();

    // ===================== Phase B: MFMA score filter =======================
    for (int u = blockIdx.x; u < 1024; u += gridDim.x) {
        float* As  = (float*)smraw;             // 64*132*4 (staging)
        float* r1  = (float*)smraw;             // 16640 B (reduction)
        float* r2  = (float*)(smraw + 16640);   // 16640 B
        float* t4b = (float*)(smraw + 33280);   // 4096 B

        const int wave = t >> 6, lane = t & 63;
        const int set   = u & 127;     // 0..127
        const int split = u >> 7;      // 0..7
        const int p0 = set * 64;
        const int b  = p0 >> 8;
        const int s0 = p0 & 255;

        __syncthreads();   // LDS-reuse guard (As overlaps previous t4b reads)
        for (int idx = t; idx < 64 * 128; idx += 256) {
            int k = idx >> 6, i = idx & 63;
            As[i * 132 + k] = out_z[(size_t)(b * NE + k) * NS + s0 + i];
        }
        __syncthreads();

        const int am = lane & 15, aq = lane >> 4;
        bf16x8 ah[4][4];
#pragma unroll
        for (int mt = 0; mt < 4; mt++)
#pragma unroll
            for (int ks = 0; ks < 4; ks++) {
                const unsigned* src = (const unsigned*)(As + (mt * 16 + am) * 132 + ks * 32 + aq * 8);
                union { unsigned uu[4]; bf16x8 v; } pk;
#pragma unroll
                for (int pr = 0; pr < 4; pr++)
                    pk.uu[pr] = (src[2 * pr + 1] & 0xFFFF0000u) | (src[2 * pr] >> 16);
                ah[mt][ks] = pk.v;
            }
        __syncthreads();

        const int Gbase = split * 32 + wave * 8;
        float cn[8];
#pragma unroll
        for (int cgi = 0; cgi < 8; cgi++)
            cn[cgi] = cnorm[(Gbase + cgi) * 16 + am];

        float b1v[16], b2v[16];
#pragma unroll
        for (int i = 0; i < 16; i++) { b1v[i] = -1e30f; b2v[i] = -1e30f; }

        bf16x8 bh[4], bhn[4];
#pragma unroll
        for (int ks = 0; ks < 4; ks++)
            bh[ks] = *(const bf16x8*)(Bpack + ((size_t)Gbase * 4 + ks) * 512 + lane * 8);

        for (int cgi = 0; cgi < 8; cgi++) {
            if (cgi < 7) {
#pragma unroll
                for (int ks = 0; ks < 4; ks++)
                    bhn[ks] = *(const bf16x8*)(Bpack + ((size_t)(Gbase + cgi + 1) * 4 + ks) * 512 + lane * 8);
            }

            f32x4 acc[4];
#pragma unroll
            for (int mt = 0; mt < 4; mt++) acc[mt] = (f32x4){0.f, 0.f, 0.f, 0.f};
#pragma unroll
            for (int ks = 0; ks < 4; ks++)
#pragma unroll
                for (int mt = 0; mt < 4; mt++)
                    acc[mt] = __builtin_amdgcn_mfma_f32_16x16x32_bf16(ah[mt][ks], bh[ks], acc[mt], 0, 0, 0);

#pragma unroll
            for (int mt = 0; mt < 4; mt++)
#pragma unroll
                for (int reg = 0; reg < 4; reg++) {
                    const int si = mt * 4 + reg;
                    float sc = acc[mt][reg] - cn[cgi];
                    float ev = asf((asu(sc) & ~7u) | (unsigned)cgi);
                    b2v[si] = fmaxf(b2v[si], fminf(ev, b1v[si]));
                    b1v[si] = fmaxf(b1v[si], ev);
                }
#pragma unroll
            for (int ks = 0; ks < 4; ks++) bh[ks] = bhn[ks];
        }

        const int slot = wave * 16 + am;
#pragma unroll
        for (int mt = 0; mt < 4; mt++)
#pragma unroll
            for (int reg = 0; reg < 4; reg++) {
                int px = mt * 16 + aq * 4 + reg;
                r1[slot * 65 + px] = b1v[mt * 4 + reg];
                r2[slot * 65 + px] = b2v[mt * 4 + reg];
            }
        __syncthreads();

        {
            const int px = t >> 2, ch = t & 3;
            float t1 = -1e30f, t2 = -1e30f, t3 = -1e30f, t4 = -1e30f;
            for (int i = 0; i < 16; i++) {
                int sl = ch * 16 + i;
#pragma unroll
                for (int e = 0; e < 2; e++) {
                    float raw = e ? r2[sl * 65 + px] : r1[sl * 65 + px];
                    unsigned vb = asu(raw);
                    float v = asf((vb & ~511u) | ((unsigned)sl << 3) | (vb & 7u));
                    t4 = fmaxf(t4, fminf(v, t3));
                    t3 = fmaxf(t3, fminf(v, t2));
                    t2 = fmaxf(t2, fminf(v, t1));
                    t1 = fmaxf(t1, v);
                }
            }
            float* dst = t4b + (px * 4 + ch) * 4;
            dst[0] = t1; dst[1] = t2; dst[2] = t3; dst[3] = t4;
        }
        __syncthreads();

        if (t < 64) {
            float u1 = -1e30f, u2 = -1e30f, u3 = -1e30f, u4 = -1e30f;
            for (int ch = 0; ch < 4; ch++) {
#pragma unroll
                for (int j = 0; j < 4; j++) {
                    float v = t4b[(t * 4 + ch) * 4 + j];
                    u4 = fmaxf(u4, fminf(v, u3));
                    u3 = fmaxf(u3, fminf(v, u2));
                    u2 = fmaxf(u2, fminf(v, u1));
                    u1 = fmaxf(u1, v);
                }
            }
            const int p = p0 + t;
            float uu[4] = { u1, u2, u3, u4 };
#pragma unroll
            for (int j = 0; j < 4; j++) {
                unsigned bits = asu(uu[j]) & 511u;
                int w = (int)(bits >> 7), res = (int)((bits >> 3) & 15u), cg2 = (int)(bits & 7u);
                pidx4[((size_t)split * NP + p) * 4 + j] = split * 512 + (w * 8 + cg2) * 16 + res;
            }
        }
    }
    grid.sync();

    // ===================== Phase C: exact f64 rescore + gather ==============
    for (int u = blockIdx.x; u < 512; u += gridDim.x) {
        float*  zl  = (float*)smraw;              // 16*132*4 = 8448 B
        double* bsl = (double*)(smraw + 8448);    // 2048 B
        int*    bil = (int*)(smraw + 10496);      // 1024 B
        int*    tok = (int*)(smraw + 11520);      // 64 B

        const int p0 = u * 16;
        const int b  = p0 >> 8;
        const int s0 = p0 & 255;

        __syncthreads();   // LDS-reuse guard
        for (int idx = t; idx < 16 * 128; idx += 256) {
            int k = idx >> 4, i = idx & 15;
            zl[i * 132 + k] = out_z[(size_t)(b * NE + k) * NS + s0 + i];
        }
        __syncthreads();

        const int il = t >> 4;   // px local 0..15
        const int cc = t & 15;   // candidate pair 0..15
        const int p  = p0 + il;
        double bs = -1e300; int bi = 0x7fffffff;
#pragma unroll
        for (int jj = 0; jj < 2; jj++) {
            int cand = cc * 2 + jj;              // 0..31
            int split = cand >> 2, slot = cand & 3;
            int idx = pidx4[((size_t)split * NP + p) * 4 + slot];
            const float* er = emb + (size_t)idx * NE;
            double dot = 0.0, nn = 0.0;
            for (int k = 0; k < NE; k += 4) {
                float4 e4 = *(const float4*)(er + k);
                dot += (double)zl[il * 132 + k + 0] * (double)e4.x;
                dot += (double)zl[il * 132 + k + 1] * (double)e4.y;
                dot += (double)zl[il * 132 + k + 2] * (double)e4.z;
                dot += (double)zl[il * 132 + k + 3] * (double)e4.w;
                nn  += (double)e4.x * e4.x + (double)e4.y * e4.y
                     + (double)e4.z * e4.z + (double)e4.w * e4.w;
            }
            double sc = dot - 0.5 * nn;
            if (sc > bs || (sc == bs && idx < bi)) { bs = sc; bi = idx; }
        }
        bsl[il * 16 + cc] = bs;
        bil[il * 16 + cc] = bi;
        __syncthreads();

        if (t < 16) {
            double B = -1e300; int I = 0x7fffffff;
            for (int c = 0; c < 16; c++) {
                double sc = bsl[t * 16 + c]; int ii = bil[t * 16 + c];
                if (sc > B || (sc == B && ii < I)) { B = sc; I = ii; }
            }
            tok[t] = I;
        }
        __syncthreads();

        for (int idx = t; idx < NE * 16; idx += 256) {
            int e = idx >> 4, i = idx & 15;
            out_zq[(size_t)(b * NE + e) * NS + s0 + i] = emb[(size_t)tok[i] * NE + e];
        }
    }
    grid.sync();

    // ===================== Phase D: post_conv ===============================
    for (int u = blockIdx.x; u < 2048; u += gridDim.x) {
        float* wtile = (float*)smraw;            // 8 KB
        float* part  = (float*)(smraw + 8192);   // 16 KB

        const int c0 = (u >> 7) * 16;
        const int b  = (u >> 2) & 31;
        const int s0 = (u & 3) * 64;

        __syncthreads();   // LDS-reuse guard
        for (int idx = t; idx < 16 * 128; idx += 256)
            wtile[idx] = post_w[(c0 + (idx >> 7)) * 128 + (idx & 127)];
        __syncthreads();

        const int kq = t >> 6, sl = t & 63;
        float acc[16];
#pragma unroll
        for (int r = 0; r < 16; r++) acc[r] = 0.f;

        const float* zin = out_zq + (size_t)(b * NE + kq * 32) * NS + s0 + sl;
        const int eb = kq * 32;
#pragma unroll 4
        for (int i = 0; i < 8; i++) {
            const int e = i * 4;
            float z0 = zin[(e + 0) * NS];
            float z1 = zin[(e + 1) * NS];
            float z2 = zin[(e + 2) * NS];
            float z3 = zin[(e + 3) * NS];
#pragma unroll
            for (int r = 0; r < 16; r++) {
                float4 w = *(const float4*)&wtile[r * 128 + eb + e];
                acc[r] = fmaf(z0, w.x, fmaf(z1, w.y, fmaf(z2, w.z, fmaf(z3, w.w, acc[r]))));
            }
        }
#pragma unroll
        for (int r = 0; r < 16; r++)
            part[(kq * 16 + r) * 64 + sl] = acc[r];
        __syncthreads();

        const int r4 = t >> 6, sl2 = t & 63;
#pragma unroll
        for (int j = 0; j < 4; j++) {
            const int r = j * 4 + r4;
            float v = post_b[c0 + r]
                    + part[(0 * 16 + r) * 64 + sl2]
                    + part[(1 * 16 + r) * 64 + sl2]
                    + part[(2 * 16 + r) * 64 + sl2]
                    + part[(3 * 16 + r) * 64 + sl2];
            out_rec[(size_t)(b * NC + c0 + r) * NS + s0 + sl2] = v;
        }
    }
}

// ===========================================================================
// Fallback path: the original validated 4-kernel pipeline (unchanged), used
// only if the cooperative launch is rejected.
// ===========================================================================
__global__ __launch_bounds__(256) void pre_conv_pack(
    const float* __restrict__ z_e, const float* __restrict__ pre_w,
    const float* __restrict__ pre_b, const float* __restrict__ emb,
    float* __restrict__ out_z, ushort_t* __restrict__ Bpack,
    float* __restrict__ cnorm)
{
    __shared__ __align__(16) float wtile[16 * 256];
    __shared__ __align__(16) float part[4 * 16 * 64];

    const int t = threadIdx.x;

    if (blockIdx.x == 8) {
        const int v     = (blockIdx.y * 4 + blockIdx.z) * 32 + (t >> 3);
        const int chunk = t & 7;
        const float4* rp = (const float4*)(emb + (size_t)v * NE + chunk * 16);
        float4 x0 = rp[0], x1 = rp[1], x2 = rp[2], x3 = rp[3];
        float xs[16] = { x0.x, x0.y, x0.z, x0.w, x1.x, x1.y, x1.z, x1.w,
                         x2.x, x2.y, x2.z, x2.w, x3.x, x3.y, x3.z, x3.w };
        us8 h0, h1;
        float nn = 0.f;
#pragma unroll
        for (int j = 0; j < 8; j++) { nn = fmaf(xs[j], xs[j], nn); h0[j] = f2bf(xs[j]); }
#pragma unroll
        for (int j = 0; j < 8; j++) { nn = fmaf(xs[8 + j], xs[8 + j], nn); h1[j] = f2bf(xs[8 + j]); }
        nn += __shfl_xor(nn, 1);
        nn += __shfl_xor(nn, 2);
        nn += __shfl_xor(nn, 4);
        if (chunk == 0) cnorm[v] = 0.5f * nn;

        const int G  = v >> 4;
        const int ks = chunk >> 1;
        const int q0 = (chunk & 1) * 2;
        const int L0 = (v & 15) | (q0 << 4);
        const int L1 = (v & 15) | ((q0 + 1) << 4);
        *(us8*)(Bpack + ((size_t)G * 4 + ks) * 512 + L0 * 8) = h0;
        *(us8*)(Bpack + ((size_t)G * 4 + ks) * 512 + L1 * 8) = h1;
        return;
    }

    const int e0 = blockIdx.x * 16;
    const int b  = blockIdx.y;
    const int s0 = blockIdx.z * 64;

    for (int idx = t; idx < 16 * 256; idx += 256)
        wtile[idx] = pre_w[(e0 + (idx >> 8)) * 256 + (idx & 255)];
    __syncthreads();

    const int kq = t >> 6, sl = t & 63;
    float acc[16];
#pragma unroll
    for (int r = 0; r < 16; r++) acc[r] = 0.f;

    const float* zin = z_e + (size_t)(b * NC + kq * 64) * NS + s0 + sl;
    const int cb = kq * 64;
#pragma unroll 4
    for (int i = 0; i < 16; i++) {
        const int c = i * 4;
        float z0 = zin[(c + 0) * NS];
        float z1 = zin[(c + 1) * NS];
        float z2 = zin[(c + 2) * NS];
        float z3 = zin[(c + 3) * NS];
#pragma unroll
        for (int r = 0; r < 16; r++) {
            float4 w = *(const float4*)&wtile[r * 256 + cb + c];
            acc[r] = fmaf(z0, w.x, fmaf(z1, w.y, fmaf(z2, w.z, fmaf(z3, w.w, acc[r]))));
        }
    }
#pragma unroll
    for (int r = 0; r < 16; r++)
        part[(kq * 16 + r) * 64 + sl] = acc[r];
    __syncthreads();

    const int r4 = t >> 6, sl2 = t & 63;
#pragma unroll
    for (int j = 0; j < 4; j++) {
        const int r = j * 4 + r4;
        float v = pre_b[e0 + r]
                + part[(0 * 16 + r) * 64 + sl2]
                + part[(1 * 16 + r) * 64 + sl2]
                + part[(2 * 16 + r) * 64 + sl2]
                + part[(3 * 16 + r) * 64 + sl2];
        out_z[(size_t)(b * NE + e0 + r) * NS + s0 + sl2] = v;
    }
}

__global__ __launch_bounds__(256, 3) void score_mfma(
    const float* __restrict__ z, const ushort_t* __restrict__ Bpack,
    const float* __restrict__ cnorm, int* __restrict__ pidx4)
{
    __shared__ __align__(16) char smraw[40960];
    float* As  = (float*)smraw;
    float* r1  = (float*)smraw;
    float* r2  = (float*)(smraw + 16640);
    float* t4b = (float*)(smraw + 33280);

    const int t = threadIdx.x;
    const int wave = t >> 6, lane = t & 63;
    const int set = blockIdx.x;
    const int split = blockIdx.y;
    const int p0 = set * 64;
    const int b  = p0 >> 8;
    const int s0 = p0 & 255;

    for (int idx = t; idx < 64 * 128; idx += 256) {
        int k = idx >> 6, i = idx & 63;
        As[i * 132 + k] = z[(size_t)(b * NE + k) * NS + s0 + i];
    }
    __syncthreads();

    const int am = lane & 15, aq = lane >> 4;
    bf16x8 ah[4][4];
#pragma unroll
    for (int mt = 0; mt < 4; mt++)
#pragma unroll
        for (int ks = 0; ks < 4; ks++) {
            const unsigned* src = (const unsigned*)(As + (mt * 16 + am) * 132 + ks * 32 + aq * 8);
            union { unsigned u[4]; bf16x8 v; } pk;
#pragma unroll
            for (int pr = 0; pr < 4; pr++)
                pk.u[pr] = (src[2 * pr + 1] & 0xFFFF0000u) | (src[2 * pr] >> 16);
            ah[mt][ks] = pk.v;
        }
    __syncthreads();

    const int Gbase = split * 32 + wave * 8;
    float cn[8];
#pragma unroll
    for (int cgi = 0; cgi < 8; cgi++)
        cn[cgi] = cnorm[(Gbase + cgi) * 16 + am];

    float b1v[16], b2v[16];
#pragma unroll
    for (int i = 0; i < 16; i++) { b1v[i] = -1e30f; b2v[i] = -1e30f; }

    bf16x8 bh[4], bhn[4];
#pragma unroll
    for (int ks = 0; ks < 4; ks++)
        bh[ks] = *(const bf16x8*)(Bpack + ((size_t)Gbase * 4 + ks) * 512 + lane * 8);

    for (int cgi = 0; cgi < 8; cgi++) {
        if (cgi < 7) {
#pragma unroll
            for (int ks = 0; ks < 4; ks++)
                bhn[ks] = *(const bf16x8*)(Bpack + ((size_t)(Gbase + cgi + 1) * 4 + ks) * 512 + lane * 8);
        }

        f32x4 acc[4];
#pragma unroll
        for (int mt = 0; mt < 4; mt++) acc[mt] = (f32x4){0.f, 0.f, 0.f, 0.f};
#pragma unroll
        for (int ks = 0; ks < 4; ks++)
#pragma unroll
            for (int mt = 0; mt < 4; mt++)
                acc[mt] = __builtin_amdgcn_mfma_f32_16x16x32_bf16(ah[mt][ks], bh[ks], acc[mt], 0, 0, 0);

#pragma unroll
        for (int mt = 0; mt < 4; mt++)
#pragma unroll
            for (int reg = 0; reg < 4; reg++) {
                const int si = mt * 4 + reg;
                float sc = acc[mt][reg] - cn[cgi];
                float ev = asf((asu(sc) & ~7u) | (unsigned)cgi);
                b2v[si] = fmaxf(b2v[si], fminf(ev, b1v[si]));
                b1v[si] = fmaxf(b1v[si], ev);
            }
#pragma unroll
        for (int ks = 0; ks < 4; ks++) bh[ks] = bhn[ks];
    }

    const int slot = wave * 16 + am;
#pragma unroll
    for (int mt = 0; mt < 4; mt++)
#pragma unroll
        for (int reg = 0; reg < 4; reg++) {
            int px = mt * 16 + aq * 4 + reg;
            r1[slot * 65 + px] = b1v[mt * 4 + reg];
            r2[slot * 65 + px] = b2v[mt * 4 + reg];
        }
    __syncthreads();

    {
        const int px = t >> 2, ch = t & 3;
        float t1 = -1e30f, t2 = -1e30f, t3 = -1e30f, t4 = -1e30f;
        for (int i = 0; i < 16; i++) {
            int sl = ch * 16 + i;
#pragma unroll
            for (int e = 0; e < 2; e++) {
                float raw = e ? r2[sl * 65 + px] : r1[sl * 65 + px];
                unsigned vb = asu(raw);
                float v = asf((vb & ~511u) | ((unsigned)sl << 3) | (vb & 7u));
                t4 = fmaxf(t4, fminf(v, t3));
                t3 = fmaxf(t3, fminf(v, t2));
                t2 = fmaxf(t2, fminf(v, t1));
                t1 = fmaxf(t1, v);
            }
        }
        float* dst = t4b + (px * 4 + ch) * 4;
        dst[0] = t1; dst[1] = t2; dst[2] = t3; dst[3] = t4;
    }
    __syncthreads();

    if (t < 64) {
        float u1 = -1e30f, u2 = -1e30f, u3 = -1e30f, u4 = -1e30f;
        for (int ch = 0; ch < 4; ch++) {
#pragma unroll
            for (int j = 0; j < 4; j++) {
                float v = t4b[(t * 4 + ch) * 4 + j];
                u4 = fmaxf(u4, fminf(v, u3));
                u3 = fmaxf(u3, fminf(v, u2));
                u2 = fmaxf(u2, fminf(v, u1));
                u1 = fmaxf(u1, v);
            }
        }
        const int p = p0 + t;
        float uu[4] = { u1, u2, u3, u4 };
#pragma unroll
        for (int j = 0; j < 4; j++) {
            unsigned bits = asu(uu[j]) & 511u;
            int w = (int)(bits >> 7), res = (int)((bits >> 3) & 15u), cg = (int)(bits & 7u);
            pidx4[((size_t)split * NP + p) * 4 + j] = split * 512 + (w * 8 + cg) * 16 + res;
        }
    }
}

__global__ __launch_bounds__(256) void rescore_gather(
    const float* __restrict__ z, const float* __restrict__ emb,
    const int* __restrict__ pidx4, float* __restrict__ out_zq)
{
    __shared__ __align__(16) float zl[16 * 132];
    __shared__ double bsl[16 * 16];
    __shared__ int    bil[16 * 16];
    __shared__ int    tok[16];

    const int t  = threadIdx.x;
    const int p0 = blockIdx.x * 16;
    const int b  = p0 >> 8;
    const int s0 = p0 & 255;

    for (int idx = t; idx < 16 * 128; idx += 256) {
        int k = idx >> 4, i = idx & 15;
        zl[i * 132 + k] = z[(size_t)(b * NE + k) * NS + s0 + i];
    }
    __syncthreads();

    const int il = t >> 4;
    const int cc = t & 15;
    const int p  = p0 + il;
    double bs = -1e300; int bi = 0x7fffffff;
#pragma unroll
    for (int jj = 0; jj < 2; jj++) {
        int cand = cc * 2 + jj;
        int split = cand >> 2, slot = cand & 3;
        int idx = pidx4[((size_t)split * NP + p) * 4 + slot];
        const float* er = emb + (size_t)idx * NE;
        double dot = 0.0, nn = 0.0;
        for (int k = 0; k < NE; k += 4) {
            float4 e4 = *(const float4*)(er + k);
            dot += (double)zl[il * 132 + k + 0] * (double)e4.x;
            dot += (double)zl[il * 132 + k + 1] * (double)e4.y;
            dot += (double)zl[il * 132 + k + 2] * (double)e4.z;
            dot += (double)zl[il * 132 + k + 3] * (double)e4.w;
            nn  += (double)e4.x * e4.x + (double)e4.y * e4.y
                 + (double)e4.z * e4.z + (double)e4.w * e4.w;
        }
        double sc = dot - 0.5 * nn;
        if (sc > bs || (sc == bs && idx < bi)) { bs = sc; bi = idx; }
    }
    bsl[il * 16 + cc] = bs;
    bil[il * 16 + cc] = bi;
    __syncthreads();

    if (t < 16) {
        double B = -1e300; int I = 0x7fffffff;
        for (int c = 0; c < 16; c++) {
            double sc = bsl[t * 16 + c]; int ii = bil[t * 16 + c];
            if (sc > B || (sc == B && ii < I)) { B = sc; I = ii; }
        }
        tok[t] = I;
    }
    __syncthreads();

    for (int idx = t; idx < NE * 16; idx += 256) {
        int e = idx >> 4, i = idx & 15;
        out_zq[(size_t)(b * NE + e) * NS + s0 + i] = emb[(size_t)tok[i] * NE + e];
    }
}

__global__ __launch_bounds__(256) void post_conv(
    const float* __restrict__ zq, const float* __restrict__ post_w,
    const float* __restrict__ post_b, float* __restrict__ out_rec)
{
    __shared__ __align__(16) float wtile[16 * 128];
    __shared__ __align__(16) float part[4 * 16 * 64];

    const int t  = threadIdx.x;
    const int c0 = blockIdx.x * 16;
    const int b  = blockIdx.y;
    const int s0 = blockIdx.z * 64;

    for (int idx = t; idx < 16 * 128; idx += 256)
        wtile[idx] = post_w[(c0 + (idx >> 7)) * 128 + (idx & 127)];
    __syncthreads();

    const int kq = t >> 6, sl = t & 63;
    float acc[16];
#pragma unroll
    for (int r = 0; r < 16; r++) acc[r] = 0.f;

    const float* zin = zq + (size_t)(b * NE + kq * 32) * NS + s0 + sl;
    const int eb = kq * 32;
#pragma unroll 4
    for (int i = 0; i < 8; i++) {
        const int e = i * 4;
        float z0 = zin[(e + 0) * NS];
        float z1 = zin[(e + 1) * NS];
        float z2 = zin[(e + 2) * NS];
        float z3 = zin[(e + 3) * NS];
#pragma unroll
        for (int r = 0; r < 16; r++) {
            float4 w = *(const float4*)&wtile[r * 128 + eb + e];
            acc[r] = fmaf(z0, w.x, fmaf(z1, w.y, fmaf(z2, w.z, fmaf(z3, w.w, acc[r]))));
        }
    }
#pragma unroll
    for (int r = 0; r < 16; r++)
        part[(kq * 16 + r) * 64 + sl] = acc[r];
    __syncthreads();

    const int r4 = t >> 6, sl2 = t & 63;
#pragma unroll
    for (int j = 0; j < 4; j++) {
        const int r = j * 4 + r4;
        float v = post_b[c0 + r]
                + part[(0 * 16 + r) * 64 + sl2]
                + part[(1 * 16 + r) * 64 + sl2]
                + part[(2 * 16 + r) * 64 + sl2]
                + part[(3 * 16 + r) * 64 + sl2];
        out_rec[(size_t)(b * NC + c0 + r) * NS + s0 + sl2] = v;
    }
}

// ---------------------------------------------------------------------------
extern "C" void kernel_launch(void* const* d_in, const int* in_sizes, int n_in,
                              void* d_out, int out_size, void* d_ws, size_t ws_size,
                              hipStream_t stream)
{
    const float* z_e    = (const float*)d_in[0];
    const float* pre_w  = (const float*)d_in[1];
    const float* pre_b  = (const float*)d_in[2];
    const float* emb    = (const float*)d_in[3];
    const float* post_w = (const float*)d_in[4];
    const float* post_b = (const float*)d_in[5];

    // d_out: fp32 x 4194304 = (z 1048576 | z_q 1048576 | rec 2097152)
    float* out     = (float*)d_out;
    float* out_z   = out;
    float* out_zq  = out + 1048576;
    float* out_rec = out + 2097152;

    // Scratch: Bpack 1 MB + cnorm 16 KB + pidx4 1 MB. Primary: d_ws;
    // fallback (constant per session): rec-region head, consumed pre-phase-D.
    const size_t SZ_BPACK = (size_t)256 * 4 * 512 * 2;            // 1 MB
    const size_t SZ_CNORM = (size_t)NV * 4;                       // 16 KB
    const size_t SZ_PIDX4 = (size_t)NSPLIT * NP * 4 * 4;          // 1 MB
    const size_t NEED = SZ_BPACK + SZ_CNORM + SZ_PIDX4;
    char* scr = (ws_size >= NEED) ? (char*)d_ws : (char*)out_rec;
    ushort_t* Bpack = (ushort_t*)scr;
    float*    cnorm = (float*)(scr + SZ_BPACK);
    int*      pidx4 = (int*)(scr + SZ_BPACK + SZ_CNORM);

    // Co-residency-validated grid for the cooperative fused kernel (cached).
    static int coopGrid = -1;
    if (coopGrid < 0) {
        int nb = 0;
        if (hipOccupancyMaxActiveBlocksPerMultiprocessor(
                &nb, (const void*)vq_fused, 256, 0) != hipSuccess || nb < 1)
            nb = 0;
        int cus = 256;
        hipDeviceProp_t prop;
        int dev = 0;
        if (hipGetDevice(&dev) == hipSuccess &&
            hipGetDeviceProperties(&prop, dev) == hipSuccess &&
            prop.multiProcessorCount > 0)
            cus = prop.multiProcessorCount;
        coopGrid = nb * cus;
        if (coopGrid > 1024) coopGrid = 1024;   // phase-B perfect balance cap
    }

    bool launched = false;
    if (coopGrid >= 1) {
        void* args[] = { (void*)&z_e, (void*)&pre_w, (void*)&pre_b, (void*)&emb,
                         (void*)&post_w, (void*)&post_b,
                         (void*)&out_z, (void*)&out_zq, (void*)&out_rec,
                         (void*)&Bpack, (void*)&cnorm, (void*)&pidx4 };
        hipError_t err = hipLaunchCooperativeKernel(
            (void*)vq_fused, dim3((unsigned)coopGrid), dim3(256), args, 0, stream);
        if (err == hipSuccess) {
            launched = true;
        } else {
            (void)hipGetLastError();   // clear error state
            coopGrid = 0;              // never retry cooperative this session
        }
    }

    if (!launched) {
        pre_conv_pack <<<dim3(9, 32, 4),     256, 0, stream>>>(z_e, pre_w, pre_b, emb,
                                                               out_z, Bpack, cnorm);
        score_mfma    <<<dim3(128, NSPLIT),  256, 0, stream>>>(out_z, Bpack, cnorm, pidx4);
        rescore_gather<<<dim3(512),          256, 0, stream>>>(out_z, emb, pidx4, out_zq);
        post_conv     <<<dim3(16, 32, 4),    256, 0, stream>>>(out_zq, post_w, post_b, out_rec);
    }
}

// Round 2
// 316.024 us; speedup vs baseline: 1.0815x; 1.0815x over previous
//
#include <hip/hip_runtime.h>
#include <hip/hip_bf16.h>
#include <hip/hip_cooperative_groups.h>
#include <cstdint>

namespace cg = cooperative_groups;

// Problem constants
#define NB   32      // batch
#define NC   256     // z channels
#define NE   128     // embed dim
#define NS   256     // H*W pixels per batch
#define NV   4096    // vocab
#define NP   8192    // total pixels
#define NSPLIT 8     // vocab splits (512 codes each)

typedef unsigned short ushort_t;
typedef __attribute__((ext_vector_type(8))) short bf16x8;
typedef __attribute__((ext_vector_type(8))) unsigned short us8;
typedef __attribute__((ext_vector_type(4))) float f32x4;

__device__ __forceinline__ float bf2f(ushort_t u) {
    union { unsigned int i; float f; } x; x.i = ((unsigned int)u) << 16; return x.f;
}
__device__ __forceinline__ ushort_t f2bf(float f) {
    __hip_bfloat16 h = __float2bfloat16(f);
    ushort_t u; __builtin_memcpy(&u, &h, 2); return u;
}
__device__ __forceinline__ unsigned asu(float f) { unsigned u; __builtin_memcpy(&u,&f,4); return u; }
__device__ __forceinline__ float    asf(unsigned u) { float f; __builtin_memcpy(&f,&u,4); return f; }

// ---------------------------------------------------------------------------
// Fused single-launch pipeline (cooperative). Phase bodies are byte-identical
// math to the validated 4-kernel version; only the work distribution changed
// (grid-stride over the old blockIdx space + grid.sync() between phases).
// LDS arena = 40960 B (max of the four phases), aliased per phase.
//
// ROUND-2 FIX: __launch_bounds__(256, 2) instead of (256, 3). Round 1's
// (256,3) capped the allocator at ~170 VGPRs while phase B needs ~180 live
// -> spill to scratch (VGPR_Count=84, +60 MB scratch writes, MfmaUtil 0.9%).
// (256,2) raises the cap to 256 VGPRs: no spill, 2 blocks/CU (LDS would
// allow 4, VGPR is binding). Grid sized by the occupancy API (expect 512).
// ---------------------------------------------------------------------------
__global__ __launch_bounds__(256, 2) void vq_fused(
    const float* __restrict__ z_e, const float* __restrict__ pre_w,
    const float* __restrict__ pre_b, const float* __restrict__ emb,
    const float* __restrict__ post_w, const float* __restrict__ post_b,
    float* __restrict__ out_z, float* __restrict__ out_zq,
    float* __restrict__ out_rec, ushort_t* __restrict__ Bpack,
    float* __restrict__ cnorm, int* __restrict__ pidx4)
{
    cg::grid_group grid = cg::this_grid();
    __shared__ __align__(16) char smraw[40960];
    const int t = threadIdx.x;

    // ===================== Phase A: pre_conv (u<1024) + pack (u>=1024) =====
    for (int u = blockIdx.x; u < 1152; u += gridDim.x) {
        if (u >= 1024) {   // ---- pack role: 128 units x 32 codes
            const int pu    = u - 1024;
            const int v     = pu * 32 + (t >> 3);
            const int chunk = t & 7;
            const float4* rp = (const float4*)(emb + (size_t)v * NE + chunk * 16);
            float4 x0 = rp[0], x1 = rp[1], x2 = rp[2], x3 = rp[3];
            float xs[16] = { x0.x, x0.y, x0.z, x0.w, x1.x, x1.y, x1.z, x1.w,
                             x2.x, x2.y, x2.z, x2.w, x3.x, x3.y, x3.z, x3.w };
            us8 h0, h1;
            float nn = 0.f;
#pragma unroll
            for (int j = 0; j < 8; j++) {
                nn = fmaf(xs[j], xs[j], nn);
                h0[j] = f2bf(xs[j]);
            }
#pragma unroll
            for (int j = 0; j < 8; j++) {
                nn = fmaf(xs[8 + j], xs[8 + j], nn);
                h1[j] = f2bf(xs[8 + j]);
            }
            nn += __shfl_xor(nn, 1);
            nn += __shfl_xor(nn, 2);
            nn += __shfl_xor(nn, 4);
            if (chunk == 0) cnorm[v] = 0.5f * nn;

            const int G  = v >> 4;
            const int ks = chunk >> 1;
            const int q0 = (chunk & 1) * 2;
            const int L0 = (v & 15) | (q0 << 4);
            const int L1 = (v & 15) | ((q0 + 1) << 4);
            *(us8*)(Bpack + ((size_t)G * 4 + ks) * 512 + L0 * 8) = h0;
            *(us8*)(Bpack + ((size_t)G * 4 + ks) * 512 + L1 * 8) = h1;
            continue;
        }

        // ---- pre_conv role
        float* wtile = (float*)smraw;            // 16 KB
        float* part  = (float*)(smraw + 16384);  // 16 KB
        const int e0 = (u >> 7) * 16;
        const int b  = (u >> 2) & 31;
        const int s0 = (u & 3) * 64;

        __syncthreads();   // LDS-reuse guard across strided units
        for (int idx = t; idx < 16 * 256; idx += 256)
            wtile[idx] = pre_w[(e0 + (idx >> 8)) * 256 + (idx & 255)];
        __syncthreads();

        const int kq = t >> 6, sl = t & 63;
        float acc[16];
#pragma unroll
        for (int r = 0; r < 16; r++) acc[r] = 0.f;

        const float* zin = z_e + (size_t)(b * NC + kq * 64) * NS + s0 + sl;
        const int cb = kq * 64;
#pragma unroll 4
        for (int i = 0; i < 16; i++) {
            const int c = i * 4;
            float z0 = zin[(c + 0) * NS];
            float z1 = zin[(c + 1) * NS];
            float z2 = zin[(c + 2) * NS];
            float z3 = zin[(c + 3) * NS];
#pragma unroll
            for (int r = 0; r < 16; r++) {
                float4 w = *(const float4*)&wtile[r * 256 + cb + c];
                acc[r] = fmaf(z0, w.x, fmaf(z1, w.y, fmaf(z2, w.z, fmaf(z3, w.w, acc[r]))));
            }
        }
#pragma unroll
        for (int r = 0; r < 16; r++)
            part[(kq * 16 + r) * 64 + sl] = acc[r];
        __syncthreads();

        const int r4 = t >> 6, sl2 = t & 63;
#pragma unroll
        for (int j = 0; j < 4; j++) {
            const int r = j * 4 + r4;
            float v = pre_b[e0 + r]
                    + part[(0 * 16 + r) * 64 + sl2]
                    + part[(1 * 16 + r) * 64 + sl2]
                    + part[(2 * 16 + r) * 64 + sl2]
                    + part[(3 * 16 + r) * 64 + sl2];
            out_z[(size_t)(b * NE + e0 + r) * NS + s0 + sl2] = v;
        }
    }
    grid.sync();

    // ===================== Phase B: MFMA score filter =======================
    for (int u = blockIdx.x; u < 1024; u += gridDim.x) {
        float* As  = (float*)smraw;             // 64*132*4 (staging)
        float* r1  = (float*)smraw;             // 16640 B (reduction)
        float* r2  = (float*)(smraw + 16640);   // 16640 B
        float* t4b = (float*)(smraw + 33280);   // 4096 B

        const int wave = t >> 6, lane = t & 63;
        const int set   = u & 127;     // 0..127
        const int split = u >> 7;      // 0..7
        const int p0 = set * 64;
        const int b  = p0 >> 8;
        const int s0 = p0 & 255;

        __syncthreads();   // LDS-reuse guard (As overlaps previous t4b reads)
        for (int idx = t; idx < 64 * 128; idx += 256) {
            int k = idx >> 6, i = idx & 63;
            As[i * 132 + k] = out_z[(size_t)(b * NE + k) * NS + s0 + i];
        }
        __syncthreads();

        const int am = lane & 15, aq = lane >> 4;
        bf16x8 ah[4][4];
#pragma unroll
        for (int mt = 0; mt < 4; mt++)
#pragma unroll
            for (int ks = 0; ks < 4; ks++) {
                const unsigned* src = (const unsigned*)(As + (mt * 16 + am) * 132 + ks * 32 + aq * 8);
                union { unsigned uu[4]; bf16x8 v; } pk;
#pragma unroll
                for (int pr = 0; pr < 4; pr++)
                    pk.uu[pr] = (src[2 * pr + 1] & 0xFFFF0000u) | (src[2 * pr] >> 16);
                ah[mt][ks] = pk.v;
            }
        __syncthreads();

        const int Gbase = split * 32 + wave * 8;
        float cn[8];
#pragma unroll
        for (int cgi = 0; cgi < 8; cgi++)
            cn[cgi] = cnorm[(Gbase + cgi) * 16 + am];

        float b1v[16], b2v[16];
#pragma unroll
        for (int i = 0; i < 16; i++) { b1v[i] = -1e30f; b2v[i] = -1e30f; }

        bf16x8 bh[4], bhn[4];
#pragma unroll
        for (int ks = 0; ks < 4; ks++)
            bh[ks] = *(const bf16x8*)(Bpack + ((size_t)Gbase * 4 + ks) * 512 + lane * 8);

        for (int cgi = 0; cgi < 8; cgi++) {
            if (cgi < 7) {
#pragma unroll
                for (int ks = 0; ks < 4; ks++)
                    bhn[ks] = *(const bf16x8*)(Bpack + ((size_t)(Gbase + cgi + 1) * 4 + ks) * 512 + lane * 8);
            }

            f32x4 acc[4];
#pragma unroll
            for (int mt = 0; mt < 4; mt++) acc[mt] = (f32x4){0.f, 0.f, 0.f, 0.f};
#pragma unroll
            for (int ks = 0; ks < 4; ks++)
#pragma unroll
                for (int mt = 0; mt < 4; mt++)
                    acc[mt] = __builtin_amdgcn_mfma_f32_16x16x32_bf16(ah[mt][ks], bh[ks], acc[mt], 0, 0, 0);

#pragma unroll
            for (int mt = 0; mt < 4; mt++)
#pragma unroll
                for (int reg = 0; reg < 4; reg++) {
                    const int si = mt * 4 + reg;
                    float sc = acc[mt][reg] - cn[cgi];
                    float ev = asf((asu(sc) & ~7u) | (unsigned)cgi);
                    b2v[si] = fmaxf(b2v[si], fminf(ev, b1v[si]));
                    b1v[si] = fmaxf(b1v[si], ev);
                }
#pragma unroll
            for (int ks = 0; ks < 4; ks++) bh[ks] = bhn[ks];
        }

        const int slot = wave * 16 + am;
#pragma unroll
        for (int mt = 0; mt < 4; mt++)
#pragma unroll
            for (int reg = 0; reg < 4; reg++) {
                int px = mt * 16 + aq * 4 + reg;
                r1[slot * 65 + px] = b1v[mt * 4 + reg];
                r2[slot * 65 + px] = b2v[mt * 4 + reg];
            }
        __syncthreads();

        {
            const int px = t >> 2, ch = t & 3;
            float t1 = -1e30f, t2 = -1e30f, t3 = -1e30f, t4 = -1e30f;
            for (int i = 0; i < 16; i++) {
                int sl = ch * 16 + i;
#pragma unroll
                for (int e = 0; e < 2; e++) {
                    float raw = e ? r2[sl * 65 + px] : r1[sl * 65 + px];
                    unsigned vb = asu(raw);
                    float v = asf((vb & ~511u) | ((unsigned)sl << 3) | (vb & 7u));
                    t4 = fmaxf(t4, fminf(v, t3));
                    t3 = fmaxf(t3, fminf(v, t2));
                    t2 = fmaxf(t2, fminf(v, t1));
                    t1 = fmaxf(t1, v);
                }
            }
            float* dst = t4b + (px * 4 + ch) * 4;
            dst[0] = t1; dst[1] = t2; dst[2] = t3; dst[3] = t4;
        }
        __syncthreads();

        if (t < 64) {
            float u1 = -1e30f, u2 = -1e30f, u3 = -1e30f, u4 = -1e30f;
            for (int ch = 0; ch < 4; ch++) {
#pragma unroll
                for (int j = 0; j < 4; j++) {
                    float v = t4b[(t * 4 + ch) * 4 + j];
                    u4 = fmaxf(u4, fminf(v, u3));
                    u3 = fmaxf(u3, fminf(v, u2));
                    u2 = fmaxf(u2, fminf(v, u1));
                    u1 = fmaxf(u1, v);
                }
            }
            const int p = p0 + t;
            float uu[4] = { u1, u2, u3, u4 };
#pragma unroll
            for (int j = 0; j < 4; j++) {
                unsigned bits = asu(uu[j]) & 511u;
                int w = (int)(bits >> 7), res = (int)((bits >> 3) & 15u), cg2 = (int)(bits & 7u);
                pidx4[((size_t)split * NP + p) * 4 + j] = split * 512 + (w * 8 + cg2) * 16 + res;
            }
        }
    }
    grid.sync();

    // ===================== Phase C: exact f64 rescore + gather ==============
    for (int u = blockIdx.x; u < 512; u += gridDim.x) {
        float*  zl  = (float*)smraw;              // 16*132*4 = 8448 B
        double* bsl = (double*)(smraw + 8448);    // 2048 B
        int*    bil = (int*)(smraw + 10496);      // 1024 B
        int*    tok = (int*)(smraw + 11520);      // 64 B

        const int p0 = u * 16;
        const int b  = p0 >> 8;
        const int s0 = p0 & 255;

        __syncthreads();   // LDS-reuse guard
        for (int idx = t; idx < 16 * 128; idx += 256) {
            int k = idx >> 4, i = idx & 15;
            zl[i * 132 + k] = out_z[(size_t)(b * NE + k) * NS + s0 + i];
        }
        __syncthreads();

        const int il = t >> 4;   // px local 0..15
        const int cc = t & 15;   // candidate pair 0..15
        const int p  = p0 + il;
        double bs = -1e300; int bi = 0x7fffffff;
#pragma unroll
        for (int jj = 0; jj < 2; jj++) {
            int cand = cc * 2 + jj;              // 0..31
            int split = cand >> 2, slot = cand & 3;
            int idx = pidx4[((size_t)split * NP + p) * 4 + slot];
            const float* er = emb + (size_t)idx * NE;
            double dot = 0.0, nn = 0.0;
            for (int k = 0; k < NE; k += 4) {
                float4 e4 = *(const float4*)(er + k);
                dot += (double)zl[il * 132 + k + 0] * (double)e4.x;
                dot += (double)zl[il * 132 + k + 1] * (double)e4.y;
                dot += (double)zl[il * 132 + k + 2] * (double)e4.z;
                dot += (double)zl[il * 132 + k + 3] * (double)e4.w;
                nn  += (double)e4.x * e4.x + (double)e4.y * e4.y
                     + (double)e4.z * e4.z + (double)e4.w * e4.w;
            }
            double sc = dot - 0.5 * nn;
            if (sc > bs || (sc == bs && idx < bi)) { bs = sc; bi = idx; }
        }
        bsl[il * 16 + cc] = bs;
        bil[il * 16 + cc] = bi;
        __syncthreads();

        if (t < 16) {
            double B = -1e300; int I = 0x7fffffff;
            for (int c = 0; c < 16; c++) {
                double sc = bsl[t * 16 + c]; int ii = bil[t * 16 + c];
                if (sc > B || (sc == B && ii < I)) { B = sc; I = ii; }
            }
            tok[t] = I;
        }
        __syncthreads();

        for (int idx = t; idx < NE * 16; idx += 256) {
            int e = idx >> 4, i = idx & 15;
            out_zq[(size_t)(b * NE + e) * NS + s0 + i] = emb[(size_t)tok[i] * NE + e];
        }
    }
    grid.sync();

    // ===================== Phase D: post_conv ===============================
    for (int u = blockIdx.x; u < 2048; u += gridDim.x) {
        float* wtile = (float*)smraw;            // 8 KB
        float* part  = (float*)(smraw + 8192);   // 16 KB

        const int c0 = (u >> 7) * 16;
        const int b  = (u >> 2) & 31;
        const int s0 = (u & 3) * 64;

        __syncthreads();   // LDS-reuse guard
        for (int idx = t; idx < 16 * 128; idx += 256)
            wtile[idx] = post_w[(c0 + (idx >> 7)) * 128 + (idx & 127)];
        __syncthreads();

        const int kq = t >> 6, sl = t & 63;
        float acc[16];
#pragma unroll
        for (int r = 0; r < 16; r++) acc[r] = 0.f;

        const float* zin = out_zq + (size_t)(b * NE + kq * 32) * NS + s0 + sl;
        const int eb = kq * 32;
#pragma unroll 4
        for (int i = 0; i < 8; i++) {
            const int e = i * 4;
            float z0 = zin[(e + 0) * NS];
            float z1 = zin[(e + 1) * NS];
            float z2 = zin[(e + 2) * NS];
            float z3 = zin[(e + 3) * NS];
#pragma unroll
            for (int r = 0; r < 16; r++) {
                float4 w = *(const float4*)&wtile[r * 128 + eb + e];
                acc[r] = fmaf(z0, w.x, fmaf(z1, w.y, fmaf(z2, w.z, fmaf(z3, w.w, acc[r]))));
            }
        }
#pragma unroll
        for (int r = 0; r < 16; r++)
            part[(kq * 16 + r) * 64 + sl] = acc[r];
        __syncthreads();

        const int r4 = t >> 6, sl2 = t & 63;
#pragma unroll
        for (int j = 0; j < 4; j++) {
            const int r = j * 4 + r4;
            float v = post_b[c0 + r]
                    + part[(0 * 16 + r) * 64 + sl2]
                    + part[(1 * 16 + r) * 64 + sl2]
                    + part[(2 * 16 + r) * 64 + sl2]
                    + part[(3 * 16 + r) * 64 + sl2];
            out_rec[(size_t)(b * NC + c0 + r) * NS + s0 + sl2] = v;
        }
    }
}

// ===========================================================================
// Fallback path: the original validated 4-kernel pipeline (unchanged), used
// only if the cooperative launch is rejected.
// ===========================================================================
__global__ __launch_bounds__(256) void pre_conv_pack(
    const float* __restrict__ z_e, const float* __restrict__ pre_w,
    const float* __restrict__ pre_b, const float* __restrict__ emb,
    float* __restrict__ out_z, ushort_t* __restrict__ Bpack,
    float* __restrict__ cnorm)
{
    __shared__ __align__(16) float wtile[16 * 256];
    __shared__ __align__(16) float part[4 * 16 * 64];

    const int t = threadIdx.x;

    if (blockIdx.x == 8) {
        const int v     = (blockIdx.y * 4 + blockIdx.z) * 32 + (t >> 3);
        const int chunk = t & 7;
        const float4* rp = (const float4*)(emb + (size_t)v * NE + chunk * 16);
        float4 x0 = rp[0], x1 = rp[1], x2 = rp[2], x3 = rp[3];
        float xs[16] = { x0.x, x0.y, x0.z, x0.w, x1.x, x1.y, x1.z, x1.w,
                         x2.x, x2.y, x2.z, x2.w, x3.x, x3.y, x3.z, x3.w };
        us8 h0, h1;
        float nn = 0.f;
#pragma unroll
        for (int j = 0; j < 8; j++) { nn = fmaf(xs[j], xs[j], nn); h0[j] = f2bf(xs[j]); }
#pragma unroll
        for (int j = 0; j < 8; j++) { nn = fmaf(xs[8 + j], xs[8 + j], nn); h1[j] = f2bf(xs[8 + j]); }
        nn += __shfl_xor(nn, 1);
        nn += __shfl_xor(nn, 2);
        nn += __shfl_xor(nn, 4);
        if (chunk == 0) cnorm[v] = 0.5f * nn;

        const int G  = v >> 4;
        const int ks = chunk >> 1;
        const int q0 = (chunk & 1) * 2;
        const int L0 = (v & 15) | (q0 << 4);
        const int L1 = (v & 15) | ((q0 + 1) << 4);
        *(us8*)(Bpack + ((size_t)G * 4 + ks) * 512 + L0 * 8) = h0;
        *(us8*)(Bpack + ((size_t)G * 4 + ks) * 512 + L1 * 8) = h1;
        return;
    }

    const int e0 = blockIdx.x * 16;
    const int b  = blockIdx.y;
    const int s0 = blockIdx.z * 64;

    for (int idx = t; idx < 16 * 256; idx += 256)
        wtile[idx] = pre_w[(e0 + (idx >> 8)) * 256 + (idx & 255)];
    __syncthreads();

    const int kq = t >> 6, sl = t & 63;
    float acc[16];
#pragma unroll
    for (int r = 0; r < 16; r++) acc[r] = 0.f;

    const float* zin = z_e + (size_t)(b * NC + kq * 64) * NS + s0 + sl;
    const int cb = kq * 64;
#pragma unroll 4
    for (int i = 0; i < 16; i++) {
        const int c = i * 4;
        float z0 = zin[(c + 0) * NS];
        float z1 = zin[(c + 1) * NS];
        float z2 = zin[(c + 2) * NS];
        float z3 = zin[(c + 3) * NS];
#pragma unroll
        for (int r = 0; r < 16; r++) {
            float4 w = *(const float4*)&wtile[r * 256 + cb + c];
            acc[r] = fmaf(z0, w.x, fmaf(z1, w.y, fmaf(z2, w.z, fmaf(z3, w.w, acc[r]))));
        }
    }
#pragma unroll
    for (int r = 0; r < 16; r++)
        part[(kq * 16 + r) * 64 + sl] = acc[r];
    __syncthreads();

    const int r4 = t >> 6, sl2 = t & 63;
#pragma unroll
    for (int j = 0; j < 4; j++) {
        const int r = j * 4 + r4;
        float v = pre_b[e0 + r]
                + part[(0 * 16 + r) * 64 + sl2]
                + part[(1 * 16 + r) * 64 + sl2]
                + part[(2 * 16 + r) * 64 + sl2]
                + part[(3 * 16 + r) * 64 + sl2];
        out_z[(size_t)(b * NE + e0 + r) * NS + s0 + sl2] = v;
    }
}

__global__ __launch_bounds__(256, 3) void score_mfma(
    const float* __restrict__ z, const ushort_t* __restrict__ Bpack,
    const float* __restrict__ cnorm, int* __restrict__ pidx4)
{
    __shared__ __align__(16) char smraw[40960];
    float* As  = (float*)smraw;
    float* r1  = (float*)smraw;
    float* r2  = (float*)(smraw + 16640);
    float* t4b = (float*)(smraw + 33280);

    const int t = threadIdx.x;
    const int wave = t >> 6, lane = t & 63;
    const int set = blockIdx.x;
    const int split = blockIdx.y;
    const int p0 = set * 64;
    const int b  = p0 >> 8;
    const int s0 = p0 & 255;

    for (int idx = t; idx < 64 * 128; idx += 256) {
        int k = idx >> 6, i = idx & 63;
        As[i * 132 + k] = z[(size_t)(b * NE + k) * NS + s0 + i];
    }
    __syncthreads();

    const int am = lane & 15, aq = lane >> 4;
    bf16x8 ah[4][4];
#pragma unroll
    for (int mt = 0; mt < 4; mt++)
#pragma unroll
        for (int ks = 0; ks < 4; ks++) {
            const unsigned* src = (const unsigned*)(As + (mt * 16 + am) * 132 + ks * 32 + aq * 8);
            union { unsigned u[4]; bf16x8 v; } pk;
#pragma unroll
            for (int pr = 0; pr < 4; pr++)
                pk.u[pr] = (src[2 * pr + 1] & 0xFFFF0000u) | (src[2 * pr] >> 16);
            ah[mt][ks] = pk.v;
        }
    __syncthreads();

    const int Gbase = split * 32 + wave * 8;
    float cn[8];
#pragma unroll
    for (int cgi = 0; cgi < 8; cgi++)
        cn[cgi] = cnorm[(Gbase + cgi) * 16 + am];

    float b1v[16], b2v[16];
#pragma unroll
    for (int i = 0; i < 16; i++) { b1v[i] = -1e30f; b2v[i] = -1e30f; }

    bf16x8 bh[4], bhn[4];
#pragma unroll
    for (int ks = 0; ks < 4; ks++)
        bh[ks] = *(const bf16x8*)(Bpack + ((size_t)Gbase * 4 + ks) * 512 + lane * 8);

    for (int cgi = 0; cgi < 8; cgi++) {
        if (cgi < 7) {
#pragma unroll
            for (int ks = 0; ks < 4; ks++)
                bhn[ks] = *(const bf16x8*)(Bpack + ((size_t)(Gbase + cgi + 1) * 4 + ks) * 512 + lane * 8);
        }

        f32x4 acc[4];
#pragma unroll
        for (int mt = 0; mt < 4; mt++) acc[mt] = (f32x4){0.f, 0.f, 0.f, 0.f};
#pragma unroll
        for (int ks = 0; ks < 4; ks++)
#pragma unroll
            for (int mt = 0; mt < 4; mt++)
                acc[mt] = __builtin_amdgcn_mfma_f32_16x16x32_bf16(ah[mt][ks], bh[ks], acc[mt], 0, 0, 0);

#pragma unroll
        for (int mt = 0; mt < 4; mt++)
#pragma unroll
            for (int reg = 0; reg < 4; reg++) {
                const int si = mt * 4 + reg;
                float sc = acc[mt][reg] - cn[cgi];
                float ev = asf((asu(sc) & ~7u) | (unsigned)cgi);
                b2v[si] = fmaxf(b2v[si], fminf(ev, b1v[si]));
                b1v[si] = fmaxf(b1v[si], ev);
            }
#pragma unroll
        for (int ks = 0; ks < 4; ks++) bh[ks] = bhn[ks];
    }

    const int slot = wave * 16 + am;
#pragma unroll
    for (int mt = 0; mt < 4; mt++)
#pragma unroll
        for (int reg = 0; reg < 4; reg++) {
            int px = mt * 16 + aq * 4 + reg;
            r1[slot * 65 + px] = b1v[mt * 4 + reg];
            r2[slot * 65 + px] = b2v[mt * 4 + reg];
        }
    __syncthreads();

    {
        const int px = t >> 2, ch = t & 3;
        float t1 = -1e30f, t2 = -1e30f, t3 = -1e30f, t4 = -1e30f;
        for (int i = 0; i < 16; i++) {
            int sl = ch * 16 + i;
#pragma unroll
            for (int e = 0; e < 2; e++) {
                float raw = e ? r2[sl * 65 + px] : r1[sl * 65 + px];
                unsigned vb = asu(raw);
                float v = asf((vb & ~511u) | ((unsigned)sl << 3) | (vb & 7u));
                t4 = fmaxf(t4, fminf(v, t3));
                t3 = fmaxf(t3, fminf(v, t2));
                t2 = fmaxf(t2, fminf(v, t1));
                t1 = fmaxf(t1, v);
            }
        }
        float* dst = t4b + (px * 4 + ch) * 4;
        dst[0] = t1; dst[1] = t2; dst[2] = t3; dst[3] = t4;
    }
    __syncthreads();

    if (t < 64) {
        float u1 = -1e30f, u2 = -1e30f, u3 = -1e30f, u4 = -1e30f;
        for (int ch = 0; ch < 4; ch++) {
#pragma unroll
            for (int j = 0; j < 4; j++) {
                float v = t4b[(t * 4 + ch) * 4 + j];
                u4 = fmaxf(u4, fminf(v, u3));
                u3 = fmaxf(u3, fminf(v, u2));
                u2 = fmaxf(u2, fminf(v, u1));
                u1 = fmaxf(u1, v);
            }
        }
        const int p = p0 + t;
        float uu[4] = { u1, u2, u3, u4 };
#pragma unroll
        for (int j = 0; j < 4; j++) {
            unsigned bits = asu(uu[j]) & 511u;
            int w = (int)(bits >> 7), res = (int)((bits >> 3) & 15u), cg = (int)(bits & 7u);
            pidx4[((size_t)split * NP + p) * 4 + j] = split * 512 + (w * 8 + cg) * 16 + res;
        }
    }
}

__global__ __launch_bounds__(256) void rescore_gather(
    const float* __restrict__ z, const float* __restrict__ emb,
    const int* __restrict__ pidx4, float* __restrict__ out_zq)
{
    __shared__ __align__(16) float zl[16 * 132];
    __shared__ double bsl[16 * 16];
    __shared__ int    bil[16 * 16];
    __shared__ int    tok[16];

    const int t  = threadIdx.x;
    const int p0 = blockIdx.x * 16;
    const int b  = p0 >> 8;
    const int s0 = p0 & 255;

    for (int idx = t; idx < 16 * 128; idx += 256) {
        int k = idx >> 4, i = idx & 15;
        zl[i * 132 + k] = z[(size_t)(b * NE + k) * NS + s0 + i];
    }
    __syncthreads();

    const int il = t >> 4;
    const int cc = t & 15;
    const int p  = p0 + il;
    double bs = -1e300; int bi = 0x7fffffff;
#pragma unroll
    for (int jj = 0; jj < 2; jj++) {
        int cand = cc * 2 + jj;
        int split = cand >> 2, slot = cand & 3;
        int idx = pidx4[((size_t)split * NP + p) * 4 + slot];
        const float* er = emb + (size_t)idx * NE;
        double dot = 0.0, nn = 0.0;
        for (int k = 0; k < NE; k += 4) {
            float4 e4 = *(const float4*)(er + k);
            dot += (double)zl[il * 132 + k + 0] * (double)e4.x;
            dot += (double)zl[il * 132 + k + 1] * (double)e4.y;
            dot += (double)zl[il * 132 + k + 2] * (double)e4.z;
            dot += (double)zl[il * 132 + k + 3] * (double)e4.w;
            nn  += (double)e4.x * e4.x + (double)e4.y * e4.y
                 + (double)e4.z * e4.z + (double)e4.w * e4.w;
        }
        double sc = dot - 0.5 * nn;
        if (sc > bs || (sc == bs && idx < bi)) { bs = sc; bi = idx; }
    }
    bsl[il * 16 + cc] = bs;
    bil[il * 16 + cc] = bi;
    __syncthreads();

    if (t < 16) {
        double B = -1e300; int I = 0x7fffffff;
        for (int c = 0; c < 16; c++) {
            double sc = bsl[t * 16 + c]; int ii = bil[t * 16 + c];
            if (sc > B || (sc == B && ii < I)) { B = sc; I = ii; }
        }
        tok[t] = I;
    }
    __syncthreads();

    for (int idx = t; idx < NE * 16; idx += 256) {
        int e = idx >> 4, i = idx & 15;
        out_zq[(size_t)(b * NE + e) * NS + s0 + i] = emb[(size_t)tok[i] * NE + e];
    }
}

__global__ __launch_bounds__(256) void post_conv(
    const float* __restrict__ zq, const float* __restrict__ post_w,
    const float* __restrict__ post_b, float* __restrict__ out_rec)
{
    __shared__ __align__(16) float wtile[16 * 128];
    __shared__ __align__(16) float part[4 * 16 * 64];

    const int t  = threadIdx.x;
    const int c0 = blockIdx.x * 16;
    const int b  = blockIdx.y;
    const int s0 = blockIdx.z * 64;

    for (int idx = t; idx < 16 * 128; idx += 256)
        wtile[idx] = post_w[(c0 + (idx >> 7)) * 128 + (idx & 127)];
    __syncthreads();

    const int kq = t >> 6, sl = t & 63;
    float acc[16];
#pragma unroll
    for (int r = 0; r < 16; r++) acc[r] = 0.f;

    const float* zin = zq + (size_t)(b * NE + kq * 32) * NS + s0 + sl;
    const int eb = kq * 32;
#pragma unroll 4
    for (int i = 0; i < 8; i++) {
        const int e = i * 4;
        float z0 = zin[(e + 0) * NS];
        float z1 = zin[(e + 1) * NS];
        float z2 = zin[(e + 2) * NS];
        float z3 = zin[(e + 3) * NS];
#pragma unroll
        for (int r = 0; r < 16; r++) {
            float4 w = *(const float4*)&wtile[r * 128 + eb + e];
            acc[r] = fmaf(z0, w.x, fmaf(z1, w.y, fmaf(z2, w.z, fmaf(z3, w.w, acc[r]))));
        }
    }
#pragma unroll
    for (int r = 0; r < 16; r++)
        part[(kq * 16 + r) * 64 + sl] = acc[r];
    __syncthreads();

    const int r4 = t >> 6, sl2 = t & 63;
#pragma unroll
    for (int j = 0; j < 4; j++) {
        const int r = j * 4 + r4;
        float v = post_b[c0 + r]
                + part[(0 * 16 + r) * 64 + sl2]
                + part[(1 * 16 + r) * 64 + sl2]
                + part[(2 * 16 + r) * 64 + sl2]
                + part[(3 * 16 + r) * 64 + sl2];
        out_rec[(size_t)(b * NC + c0 + r) * NS + s0 + sl2] = v;
    }
}

// ---------------------------------------------------------------------------
extern "C" void kernel_launch(void* const* d_in, const int* in_sizes, int n_in,
                              void* d_out, int out_size, void* d_ws, size_t ws_size,
                              hipStream_t stream)
{
    const float* z_e    = (const float*)d_in[0];
    const float* pre_w  = (const float*)d_in[1];
    const float* pre_b  = (const float*)d_in[2];
    const float* emb    = (const float*)d_in[3];
    const float* post_w = (const float*)d_in[4];
    const float* post_b = (const float*)d_in[5];

    // d_out: fp32 x 4194304 = (z 1048576 | z_q 1048576 | rec 2097152)
    float* out     = (float*)d_out;
    float* out_z   = out;
    float* out_zq  = out + 1048576;
    float* out_rec = out + 2097152;

    // Scratch: Bpack 1 MB + cnorm 16 KB + pidx4 1 MB. Primary: d_ws;
    // fallback (constant per session): rec-region head, consumed pre-phase-D.
    const size_t SZ_BPACK = (size_t)256 * 4 * 512 * 2;            // 1 MB
    const size_t SZ_CNORM = (size_t)NV * 4;                       // 16 KB
    const size_t SZ_PIDX4 = (size_t)NSPLIT * NP * 4 * 4;          // 1 MB
    const size_t NEED = SZ_BPACK + SZ_CNORM + SZ_PIDX4;
    char* scr = (ws_size >= NEED) ? (char*)d_ws : (char*)out_rec;
    ushort_t* Bpack = (ushort_t*)scr;
    float*    cnorm = (float*)(scr + SZ_BPACK);
    int*      pidx4 = (int*)(scr + SZ_BPACK + SZ_CNORM);

    // Co-residency-validated grid for the cooperative fused kernel (cached).
    static int coopGrid = -1;
    if (coopGrid < 0) {
        int nb = 0;
        if (hipOccupancyMaxActiveBlocksPerMultiprocessor(
                &nb, (const void*)vq_fused, 256, 0) != hipSuccess || nb < 1)
            nb = 0;
        int cus = 256;
        hipDeviceProp_t prop;
        int dev = 0;
        if (hipGetDevice(&dev) == hipSuccess &&
            hipGetDeviceProperties(&prop, dev) == hipSuccess &&
            prop.multiProcessorCount > 0)
            cus = prop.multiProcessorCount;
        coopGrid = nb * cus;
        if (coopGrid > 1024) coopGrid = 1024;   // phase-B perfect balance cap
    }

    bool launched = false;
    if (coopGrid >= 1) {
        void* args[] = { (void*)&z_e, (void*)&pre_w, (void*)&pre_b, (void*)&emb,
                         (void*)&post_w, (void*)&post_b,
                         (void*)&out_z, (void*)&out_zq, (void*)&out_rec,
                         (void*)&Bpack, (void*)&cnorm, (void*)&pidx4 };
        hipError_t err = hipLaunchCooperativeKernel(
            (void*)vq_fused, dim3((unsigned)coopGrid), dim3(256), args, 0, stream);
        if (err == hipSuccess) {
            launched = true;
        } else {
            (void)hipGetLastError();   // clear error state
            coopGrid = 0;              // never retry cooperative this session
        }
    }

    if (!launched) {
        pre_conv_pack <<<dim3(9, 32, 4),     256, 0, stream>>>(z_e, pre_w, pre_b, emb,
                                                               out_z, Bpack, cnorm);
        score_mfma    <<<dim3(128, NSPLIT),  256, 0, stream>>>(out_z, Bpack, cnorm, pidx4);
        rescore_gather<<<dim3(512),          256, 0, stream>>>(out_z, emb, pidx4, out_zq);
        post_conv     <<<dim3(16, 32, 4),    256, 0, stream>>>(out_zq, post_w, post_b, out_rec);
    }
}

// Round 3
// 158.635 us; speedup vs baseline: 2.1546x; 1.9921x over previous
//
#include <hip/hip_runtime.h>
#include <hip/hip_bf16.h>
#include <cstdint>

// Problem constants
#define NB   32      // batch
#define NC   256     // z channels
#define NE   128     // embed dim
#define NS   256     // H*W pixels per batch
#define NV   4096    // vocab
#define NP   8192    // total pixels
#define NSPLIT 8     // vocab splits (512 codes each)

typedef unsigned short ushort_t;
typedef __attribute__((ext_vector_type(8))) short bf16x8;
typedef __attribute__((ext_vector_type(8))) unsigned short us8;
typedef __attribute__((ext_vector_type(4))) float f32x4;

__device__ __forceinline__ float bf2f(ushort_t u) {
    union { unsigned int i; float f; } x; x.i = ((unsigned int)u) << 16; return x.f;
}
__device__ __forceinline__ ushort_t f2bf(float f) {
    __hip_bfloat16 h = __float2bfloat16(f);
    ushort_t u; __builtin_memcpy(&u, &h, 2); return u;
}
__device__ __forceinline__ unsigned asu(float f) { unsigned u; __builtin_memcpy(&u,&f,4); return u; }
__device__ __forceinline__ float    asf(unsigned u) { float f; __builtin_memcpy(&f,&u,4); return f; }

// ---------------------------------------------------------------------------
// K1 (fused):
//  bx<8  -> pre_conv: z = pre_w @ z_e + pre_b. Grid (8 e-tiles, 32 b, 4 s-blk)
//           = 1024 blocks; LDS-staged weights; k split 4 ways across waves
//           (16-step dependent chains); LDS partial-sum reduction.
//  bx==8 -> pack emb hi-bf16 into Bpack (MFMA B-frag order) + cnorm.
//           128 blocks (by,bz) x 32 codes, 8 lanes/code, shfl norm-reduce.
// Bpack (ushort units): [(G*4 + ks)*512 + L*8 + j],
//   element = emb[code = G*16 + (L&15)][k = ks*32 + (L>>4)*8 + j]
// ---------------------------------------------------------------------------
__global__ __launch_bounds__(256) void pre_conv_pack(
    const float* __restrict__ z_e, const float* __restrict__ pre_w,
    const float* __restrict__ pre_b, const float* __restrict__ emb,
    float* __restrict__ out_z, ushort_t* __restrict__ Bpack,
    float* __restrict__ cnorm)
{
    __shared__ __align__(16) float wtile[16 * 256];   // 16 KB
    __shared__ __align__(16) float part[4 * 16 * 64]; // 16 KB

    const int t = threadIdx.x;

    if (blockIdx.x == 8) {   // ---- pack role
        const int v     = (blockIdx.y * 4 + blockIdx.z) * 32 + (t >> 3);
        const int chunk = t & 7;
        const float4* rp = (const float4*)(emb + (size_t)v * NE + chunk * 16);
        float4 x0 = rp[0], x1 = rp[1], x2 = rp[2], x3 = rp[3];
        float xs[16] = { x0.x, x0.y, x0.z, x0.w, x1.x, x1.y, x1.z, x1.w,
                         x2.x, x2.y, x2.z, x2.w, x3.x, x3.y, x3.z, x3.w };
        us8 h0, h1;
        float nn = 0.f;
#pragma unroll
        for (int j = 0; j < 8; j++) {
            nn = fmaf(xs[j], xs[j], nn);
            h0[j] = f2bf(xs[j]);
        }
#pragma unroll
        for (int j = 0; j < 8; j++) {
            nn = fmaf(xs[8 + j], xs[8 + j], nn);
            h1[j] = f2bf(xs[8 + j]);
        }
        nn += __shfl_xor(nn, 1);
        nn += __shfl_xor(nn, 2);
        nn += __shfl_xor(nn, 4);
        if (chunk == 0) cnorm[v] = 0.5f * nn;

        const int G  = v >> 4;
        const int ks = chunk >> 1;
        const int q0 = (chunk & 1) * 2;
        const int L0 = (v & 15) | (q0 << 4);
        const int L1 = (v & 15) | ((q0 + 1) << 4);
        *(us8*)(Bpack + ((size_t)G * 4 + ks) * 512 + L0 * 8) = h0;
        *(us8*)(Bpack + ((size_t)G * 4 + ks) * 512 + L1 * 8) = h1;
        return;
    }

    // ---- pre_conv role
    const int e0 = blockIdx.x * 16;
    const int b  = blockIdx.y;
    const int s0 = blockIdx.z * 64;

    for (int idx = t; idx < 16 * 256; idx += 256)
        wtile[idx] = pre_w[(e0 + (idx >> 8)) * 256 + (idx & 255)];
    __syncthreads();

    const int kq = t >> 6, sl = t & 63;
    float acc[16];
#pragma unroll
    for (int r = 0; r < 16; r++) acc[r] = 0.f;

    const float* zin = z_e + (size_t)(b * NC + kq * 64) * NS + s0 + sl;
    const int cb = kq * 64;
#pragma unroll 4
    for (int i = 0; i < 16; i++) {
        const int c = i * 4;
        float z0 = zin[(c + 0) * NS];
        float z1 = zin[(c + 1) * NS];
        float z2 = zin[(c + 2) * NS];
        float z3 = zin[(c + 3) * NS];
#pragma unroll
        for (int r = 0; r < 16; r++) {
            float4 w = *(const float4*)&wtile[r * 256 + cb + c];
            acc[r] = fmaf(z0, w.x, fmaf(z1, w.y, fmaf(z2, w.z, fmaf(z3, w.w, acc[r]))));
        }
    }
#pragma unroll
    for (int r = 0; r < 16; r++)
        part[(kq * 16 + r) * 64 + sl] = acc[r];
    __syncthreads();

    const int r4 = t >> 6, sl2 = t & 63;
#pragma unroll
    for (int j = 0; j < 4; j++) {
        const int r = j * 4 + r4;
        float v = pre_b[e0 + r]
                + part[(0 * 16 + r) * 64 + sl2]
                + part[(1 * 16 + r) * 64 + sl2]
                + part[(2 * 16 + r) * 64 + sl2]
                + part[(3 * 16 + r) * 64 + sl2];
        out_z[(size_t)(b * NE + e0 + r) * NS + s0 + sl2] = v;
    }
}

// ---------------------------------------------------------------------------
// K2: MFMA score filter (validated, unchanged). Single bf16 term;
// per-lane top-2 per 8-code slot; block top-4 per split -> pidx4.
// ---------------------------------------------------------------------------
__global__ __launch_bounds__(256, 3) void score_mfma(
    const float* __restrict__ z, const ushort_t* __restrict__ Bpack,
    const float* __restrict__ cnorm, int* __restrict__ pidx4)
{
    __shared__ __align__(16) char smraw[40960];
    float* As  = (float*)smraw;             // 64*132*4 = 33792 B (staging)
    float* r1  = (float*)smraw;             // 64*65*4  = 16640 B (reduction)
    float* r2  = (float*)(smraw + 16640);   // 16640 B
    float* t4b = (float*)(smraw + 33280);   // 4096 B

    const int t = threadIdx.x;
    const int wave = t >> 6, lane = t & 63;
    const int set = blockIdx.x;      // 0..127
    const int split = blockIdx.y;    // 0..7
    const int p0 = set * 64;
    const int b  = p0 >> 8;
    const int s0 = p0 & 255;

    for (int idx = t; idx < 64 * 128; idx += 256) {
        int k = idx >> 6, i = idx & 63;
        As[i * 132 + k] = z[(size_t)(b * NE + k) * NS + s0 + i];
    }
    __syncthreads();

    const int am = lane & 15, aq = lane >> 4;
    bf16x8 ah[4][4];
#pragma unroll
    for (int mt = 0; mt < 4; mt++)
#pragma unroll
        for (int ks = 0; ks < 4; ks++) {
            const unsigned* src = (const unsigned*)(As + (mt * 16 + am) * 132 + ks * 32 + aq * 8);
            union { unsigned u[4]; bf16x8 v; } pk;
#pragma unroll
            for (int pr = 0; pr < 4; pr++)
                pk.u[pr] = (src[2 * pr + 1] & 0xFFFF0000u) | (src[2 * pr] >> 16);
            ah[mt][ks] = pk.v;
        }
    __syncthreads();

    const int Gbase = split * 32 + wave * 8;
    float cn[8];
#pragma unroll
    for (int cgi = 0; cgi < 8; cgi++)
        cn[cgi] = cnorm[(Gbase + cgi) * 16 + am];

    float b1v[16], b2v[16];
#pragma unroll
    for (int i = 0; i < 16; i++) { b1v[i] = -1e30f; b2v[i] = -1e30f; }

    bf16x8 bh[4], bhn[4];
#pragma unroll
    for (int ks = 0; ks < 4; ks++)
        bh[ks] = *(const bf16x8*)(Bpack + ((size_t)Gbase * 4 + ks) * 512 + lane * 8);

    for (int cgi = 0; cgi < 8; cgi++) {
        if (cgi < 7) {
#pragma unroll
            for (int ks = 0; ks < 4; ks++)
                bhn[ks] = *(const bf16x8*)(Bpack + ((size_t)(Gbase + cgi + 1) * 4 + ks) * 512 + lane * 8);
        }

        f32x4 acc[4];
#pragma unroll
        for (int mt = 0; mt < 4; mt++) acc[mt] = (f32x4){0.f, 0.f, 0.f, 0.f};
#pragma unroll
        for (int ks = 0; ks < 4; ks++)
#pragma unroll
            for (int mt = 0; mt < 4; mt++)
                acc[mt] = __builtin_amdgcn_mfma_f32_16x16x32_bf16(ah[mt][ks], bh[ks], acc[mt], 0, 0, 0);

#pragma unroll
        for (int mt = 0; mt < 4; mt++)
#pragma unroll
            for (int reg = 0; reg < 4; reg++) {
                const int si = mt * 4 + reg;
                float sc = acc[mt][reg] - cn[cgi];
                float ev = asf((asu(sc) & ~7u) | (unsigned)cgi);
                b2v[si] = fmaxf(b2v[si], fminf(ev, b1v[si]));
                b1v[si] = fmaxf(b1v[si], ev);
            }
#pragma unroll
        for (int ks = 0; ks < 4; ks++) bh[ks] = bhn[ks];
    }

    const int slot = wave * 16 + am;
#pragma unroll
    for (int mt = 0; mt < 4; mt++)
#pragma unroll
        for (int reg = 0; reg < 4; reg++) {
            int px = mt * 16 + aq * 4 + reg;
            r1[slot * 65 + px] = b1v[mt * 4 + reg];
            r2[slot * 65 + px] = b2v[mt * 4 + reg];
        }
    __syncthreads();

    {
        const int px = t >> 2, ch = t & 3;
        float t1 = -1e30f, t2 = -1e30f, t3 = -1e30f, t4 = -1e30f;
        for (int i = 0; i < 16; i++) {
            int sl = ch * 16 + i;
#pragma unroll
            for (int e = 0; e < 2; e++) {
                float raw = e ? r2[sl * 65 + px] : r1[sl * 65 + px];
                unsigned vb = asu(raw);
                float v = asf((vb & ~511u) | ((unsigned)sl << 3) | (vb & 7u));
                t4 = fmaxf(t4, fminf(v, t3));
                t3 = fmaxf(t3, fminf(v, t2));
                t2 = fmaxf(t2, fminf(v, t1));
                t1 = fmaxf(t1, v);
            }
        }
        float* dst = t4b + (px * 4 + ch) * 4;
        dst[0] = t1; dst[1] = t2; dst[2] = t3; dst[3] = t4;
    }
    __syncthreads();

    if (t < 64) {
        float u1 = -1e30f, u2 = -1e30f, u3 = -1e30f, u4 = -1e30f;
        for (int ch = 0; ch < 4; ch++) {
#pragma unroll
            for (int j = 0; j < 4; j++) {
                float v = t4b[(t * 4 + ch) * 4 + j];
                u4 = fmaxf(u4, fminf(v, u3));
                u3 = fmaxf(u3, fminf(v, u2));
                u2 = fmaxf(u2, fminf(v, u1));
                u1 = fmaxf(u1, v);
            }
        }
        const int p = p0 + t;
        float uu[4] = { u1, u2, u3, u4 };
#pragma unroll
        for (int j = 0; j < 4; j++) {
            unsigned bits = asu(uu[j]) & 511u;
            int w = (int)(bits >> 7), res = (int)((bits >> 3) & 15u), cg = (int)(bits & 7u);
            pidx4[((size_t)split * NP + p) * 4 + j] = split * 512 + (w * 8 + cg) * 16 + res;
        }
    }
}

// ---------------------------------------------------------------------------
// K3' (merged K3+K4): exact f64 rescore of the 32 candidates/px, pick token
// (tie -> lowest idx == np.argmin), gather z_q = emb[token] (written to
// out_zq AND staged in LDS), then post_conv for the same 16 px:
// rec[c][px] = post_w[c,:]·eg[px,:] + post_b[c], 4 c-tiles of 64, 4-px
// register blocking (4x weight reuse vs old K4), conflict-free padded LDS,
// LDS-transposed coalesced store. 512 blocks x 16 px.
// ---------------------------------------------------------------------------
__global__ __launch_bounds__(256) void rescore_gather_post(
    const float* __restrict__ z, const float* __restrict__ emb,
    const int* __restrict__ pidx4, const float* __restrict__ post_w,
    const float* __restrict__ post_b, float* __restrict__ out_zq,
    float* __restrict__ out_rec)
{
    __shared__ __align__(16) float zl[16 * 132];    // 8448 B
    __shared__ double bsl[16 * 16];                 // 2048 B
    __shared__ int    bil[16 * 16];                 // 1024 B
    __shared__ int    tok[16];                      //   64 B
    __shared__ __align__(16) float eg[16 * 132];    // 8448 B (z_q rows, [px][k])
    __shared__ __align__(16) float wtile[64 * 129]; // 33024 B (c-tile of post_w)
    __shared__ float  outb[64 * 17];                // 4352 B (transpose buffer)

    const int t  = threadIdx.x;
    const int p0 = blockIdx.x * 16;
    const int b  = p0 >> 8;
    const int s0 = p0 & 255;

    // ---- stage z rows (identical to validated K3) ----
    for (int idx = t; idx < 16 * 128; idx += 256) {
        int k = idx >> 4, i = idx & 15;
        zl[i * 132 + k] = z[(size_t)(b * NE + k) * NS + s0 + i];
    }
    __syncthreads();

    // ---- exact f64 rescore, 16 threads/px x 2 candidates ----
    const int il = t >> 4;   // px local 0..15
    const int cc = t & 15;   // candidate pair 0..15
    const int p  = p0 + il;
    double bs = -1e300; int bi = 0x7fffffff;
#pragma unroll
    for (int jj = 0; jj < 2; jj++) {
        int cand = cc * 2 + jj;              // 0..31
        int split = cand >> 2, slot = cand & 3;
        int idx = pidx4[((size_t)split * NP + p) * 4 + slot];
        const float* er = emb + (size_t)idx * NE;
        double dot = 0.0, nn = 0.0;
        for (int k = 0; k < NE; k += 4) {
            float4 e4 = *(const float4*)(er + k);
            dot += (double)zl[il * 132 + k + 0] * (double)e4.x;
            dot += (double)zl[il * 132 + k + 1] * (double)e4.y;
            dot += (double)zl[il * 132 + k + 2] * (double)e4.z;
            dot += (double)zl[il * 132 + k + 3] * (double)e4.w;
            nn  += (double)e4.x * e4.x + (double)e4.y * e4.y
                 + (double)e4.z * e4.z + (double)e4.w * e4.w;
        }
        double sc = dot - 0.5 * nn;
        if (sc > bs || (sc == bs && idx < bi)) { bs = sc; bi = idx; }
    }
    bsl[il * 16 + cc] = bs;
    bil[il * 16 + cc] = bi;
    __syncthreads();

    if (t < 16) {
        double B = -1e300; int I = 0x7fffffff;
        for (int c = 0; c < 16; c++) {
            double sc = bsl[t * 16 + c]; int ii = bil[t * 16 + c];
            if (sc > B || (sc == B && ii < I)) { B = sc; I = ii; }
        }
        tok[t] = I;
    }
    __syncthreads();

    // ---- gather: write out_zq and stage eg[px][k] in LDS ----
    for (int idx = t; idx < NE * 16; idx += 256) {
        int e = idx >> 4, i = idx & 15;
        float v = emb[(size_t)tok[i] * NE + e];
        out_zq[(size_t)(b * NE + e) * NS + s0 + i] = v;
        eg[i * 132 + e] = v;
    }
    __syncthreads();

    // ---- post_conv: rec[c][px], 4 c-tiles of 64, thread = (wave=4px, cl=c) ----
    const int pg  = t >> 6;        // wave -> px group (4 px)
    const int cl  = t & 63;        // c within tile
    const int px0 = pg * 4;
    const float* g0 = &eg[(px0 + 0) * 132];
    const float* g1 = &eg[(px0 + 1) * 132];
    const float* g2 = &eg[(px0 + 2) * 132];
    const float* g3 = &eg[(px0 + 3) * 132];

    for (int ct = 0; ct < 4; ct++) {
        // stage 64x128 weight tile, padded leading dim 129 (conflict-free)
        for (int idx = t; idx < 64 * 128; idx += 256) {
            int r = idx >> 7, k = idx & 127;
            wtile[r * 129 + k] = post_w[(size_t)(ct * 64 + r) * 128 + k];
        }
        __syncthreads();

        float a0 = 0.f, a1 = 0.f, a2 = 0.f, a3 = 0.f;
        const float* wr = &wtile[cl * 129];
#pragma unroll 4
        for (int k = 0; k < 128; k += 4) {
            float w0 = wr[k + 0], w1 = wr[k + 1], w2 = wr[k + 2], w3 = wr[k + 3];
            float4 q0 = *(const float4*)&g0[k];
            float4 q1 = *(const float4*)&g1[k];
            float4 q2 = *(const float4*)&g2[k];
            float4 q3 = *(const float4*)&g3[k];
            a0 = fmaf(w0, q0.x, fmaf(w1, q0.y, fmaf(w2, q0.z, fmaf(w3, q0.w, a0))));
            a1 = fmaf(w0, q1.x, fmaf(w1, q1.y, fmaf(w2, q1.z, fmaf(w3, q1.w, a1))));
            a2 = fmaf(w0, q2.x, fmaf(w1, q2.y, fmaf(w2, q2.z, fmaf(w3, q2.w, a2))));
            a3 = fmaf(w0, q3.x, fmaf(w1, q3.y, fmaf(w2, q3.z, fmaf(w3, q3.w, a3))));
        }
        float bias = post_b[ct * 64 + cl];
        outb[cl * 17 + px0 + 0] = a0 + bias;
        outb[cl * 17 + px0 + 1] = a1 + bias;
        outb[cl * 17 + px0 + 2] = a2 + bias;
        outb[cl * 17 + px0 + 3] = a3 + bias;
        __syncthreads();

        // coalesced store via LDS transpose: wave covers 4 c-rows x 16 px
        for (int idx = t; idx < 64 * 16; idx += 256) {
            int c_loc = idx >> 4, px = idx & 15;
            out_rec[(size_t)(b * NC + ct * 64 + c_loc) * NS + s0 + px] =
                outb[c_loc * 17 + px];
        }
        // no trailing barrier needed: next stage writes wtile only (disjoint
        // from outb), and the next stage's post-barrier orders everything.
        __syncthreads();
    }
}

// ---------------------------------------------------------------------------
extern "C" void kernel_launch(void* const* d_in, const int* in_sizes, int n_in,
                              void* d_out, int out_size, void* d_ws, size_t ws_size,
                              hipStream_t stream)
{
    const float* z_e    = (const float*)d_in[0];
    const float* pre_w  = (const float*)d_in[1];
    const float* pre_b  = (const float*)d_in[2];
    const float* emb    = (const float*)d_in[3];
    const float* post_w = (const float*)d_in[4];
    const float* post_b = (const float*)d_in[5];

    // d_out: fp32 x 4194304 = (z 1048576 | z_q 1048576 | rec 2097152)
    float* out     = (float*)d_out;
    float* out_z   = out;
    float* out_zq  = out + 1048576;
    float* out_rec = out + 2097152;

    // Scratch: Bpack 1 MB + cnorm 16 KB + pidx4 1 MB. Primary: d_ws;
    // fallback (constant per session): rec-region head, consumed before the
    // rec writes of the final kernel touch it only after pidx4 reads... the
    // d_ws path has always been taken in this harness (ws_size >= 2 MB).
    const size_t SZ_BPACK = (size_t)256 * 4 * 512 * 2;            // 1 MB
    const size_t SZ_CNORM = (size_t)NV * 4;                       // 16 KB
    const size_t SZ_PIDX4 = (size_t)NSPLIT * NP * 4 * 4;          // 1 MB
    const size_t NEED = SZ_BPACK + SZ_CNORM + SZ_PIDX4;
    char* scr = (ws_size >= NEED) ? (char*)d_ws : (char*)out_rec;
    ushort_t* Bpack = (ushort_t*)scr;
    float*    cnorm = (float*)(scr + SZ_BPACK);
    int*      pidx4 = (int*)(scr + SZ_BPACK + SZ_CNORM);

    pre_conv_pack      <<<dim3(9, 32, 4),    256, 0, stream>>>(z_e, pre_w, pre_b, emb,
                                                               out_z, Bpack, cnorm);
    score_mfma         <<<dim3(128, NSPLIT), 256, 0, stream>>>(out_z, Bpack, cnorm, pidx4);
    rescore_gather_post<<<dim3(512),         256, 0, stream>>>(out_z, emb, pidx4,
                                                               post_w, post_b,
                                                               out_zq, out_rec);
}

// Round 4
// 152.855 us; speedup vs baseline: 2.2360x; 1.0378x over previous
//
#include <hip/hip_runtime.h>
#include <hip/hip_bf16.h>
#include <cstdint>

// Problem constants
#define NB   32      // batch
#define NC   256     // z channels
#define NE   128     // embed dim
#define NS   256     // H*W pixels per batch
#define NV   4096    // vocab
#define NP   8192    // total pixels
#define NSPLIT 8     // vocab splits (512 codes each)

typedef unsigned short ushort_t;
typedef __attribute__((ext_vector_type(8))) short bf16x8;
typedef __attribute__((ext_vector_type(8))) unsigned short us8;
typedef __attribute__((ext_vector_type(4))) float f32x4;

__device__ __forceinline__ float bf2f(ushort_t u) {
    union { unsigned int i; float f; } x; x.i = ((unsigned int)u) << 16; return x.f;
}
__device__ __forceinline__ ushort_t f2bf(float f) {
    __hip_bfloat16 h = __float2bfloat16(f);
    ushort_t u; __builtin_memcpy(&u, &h, 2); return u;
}
__device__ __forceinline__ unsigned asu(float f) { unsigned u; __builtin_memcpy(&u,&f,4); return u; }
__device__ __forceinline__ float    asf(unsigned u) { float f; __builtin_memcpy(&f,&u,4); return f; }

// ---------------------------------------------------------------------------
// K1 (fused):
//  bx<8  -> pre_conv: z = pre_w @ z_e + pre_b. Grid (8 e-tiles, 32 b, 4 s-blk)
//           = 1024 blocks; LDS-staged weights; k split 4 ways across waves
//           (16-step dependent chains); LDS partial-sum reduction.
//  bx==8 -> pack emb hi-bf16 into Bpack (MFMA B-frag order) + cnorm.
//           128 blocks (by,bz) x 32 codes, 8 lanes/code, shfl norm-reduce.
// Bpack (ushort units): [(G*4 + ks)*512 + L*8 + j],
//   element = emb[code = G*16 + (L&15)][k = ks*32 + (L>>4)*8 + j]
// ---------------------------------------------------------------------------
__global__ __launch_bounds__(256) void pre_conv_pack(
    const float* __restrict__ z_e, const float* __restrict__ pre_w,
    const float* __restrict__ pre_b, const float* __restrict__ emb,
    float* __restrict__ out_z, ushort_t* __restrict__ Bpack,
    float* __restrict__ cnorm)
{
    __shared__ __align__(16) float wtile[16 * 256];   // 16 KB
    __shared__ __align__(16) float part[4 * 16 * 64]; // 16 KB

    const int t = threadIdx.x;

    if (blockIdx.x == 8) {   // ---- pack role
        const int v     = (blockIdx.y * 4 + blockIdx.z) * 32 + (t >> 3);
        const int chunk = t & 7;
        const float4* rp = (const float4*)(emb + (size_t)v * NE + chunk * 16);
        float4 x0 = rp[0], x1 = rp[1], x2 = rp[2], x3 = rp[3];
        float xs[16] = { x0.x, x0.y, x0.z, x0.w, x1.x, x1.y, x1.z, x1.w,
                         x2.x, x2.y, x2.z, x2.w, x3.x, x3.y, x3.z, x3.w };
        us8 h0, h1;
        float nn = 0.f;
#pragma unroll
        for (int j = 0; j < 8; j++) {
            nn = fmaf(xs[j], xs[j], nn);
            h0[j] = f2bf(xs[j]);
        }
#pragma unroll
        for (int j = 0; j < 8; j++) {
            nn = fmaf(xs[8 + j], xs[8 + j], nn);
            h1[j] = f2bf(xs[8 + j]);
        }
        nn += __shfl_xor(nn, 1);
        nn += __shfl_xor(nn, 2);
        nn += __shfl_xor(nn, 4);
        if (chunk == 0) cnorm[v] = 0.5f * nn;

        const int G  = v >> 4;
        const int ks = chunk >> 1;
        const int q0 = (chunk & 1) * 2;
        const int L0 = (v & 15) | (q0 << 4);
        const int L1 = (v & 15) | ((q0 + 1) << 4);
        *(us8*)(Bpack + ((size_t)G * 4 + ks) * 512 + L0 * 8) = h0;
        *(us8*)(Bpack + ((size_t)G * 4 + ks) * 512 + L1 * 8) = h1;
        return;
    }

    // ---- pre_conv role
    const int e0 = blockIdx.x * 16;
    const int b  = blockIdx.y;
    const int s0 = blockIdx.z * 64;

    for (int idx = t; idx < 16 * 256; idx += 256)
        wtile[idx] = pre_w[(e0 + (idx >> 8)) * 256 + (idx & 255)];
    __syncthreads();

    const int kq = t >> 6, sl = t & 63;
    float acc[16];
#pragma unroll
    for (int r = 0; r < 16; r++) acc[r] = 0.f;

    const float* zin = z_e + (size_t)(b * NC + kq * 64) * NS + s0 + sl;
    const int cb = kq * 64;
#pragma unroll 4
    for (int i = 0; i < 16; i++) {
        const int c = i * 4;
        float z0 = zin[(c + 0) * NS];
        float z1 = zin[(c + 1) * NS];
        float z2 = zin[(c + 2) * NS];
        float z3 = zin[(c + 3) * NS];
#pragma unroll
        for (int r = 0; r < 16; r++) {
            float4 w = *(const float4*)&wtile[r * 256 + cb + c];
            acc[r] = fmaf(z0, w.x, fmaf(z1, w.y, fmaf(z2, w.z, fmaf(z3, w.w, acc[r]))));
        }
    }
#pragma unroll
    for (int r = 0; r < 16; r++)
        part[(kq * 16 + r) * 64 + sl] = acc[r];
    __syncthreads();

    const int r4 = t >> 6, sl2 = t & 63;
#pragma unroll
    for (int j = 0; j < 4; j++) {
        const int r = j * 4 + r4;
        float v = pre_b[e0 + r]
                + part[(0 * 16 + r) * 64 + sl2]
                + part[(1 * 16 + r) * 64 + sl2]
                + part[(2 * 16 + r) * 64 + sl2]
                + part[(3 * 16 + r) * 64 + sl2];
        out_z[(size_t)(b * NE + e0 + r) * NS + s0 + sl2] = v;
    }
}

// ---------------------------------------------------------------------------
// K2: MFMA score filter (validated, unchanged). Single bf16 term;
// per-lane top-2 per 8-code slot; block top-4 per split -> pidx4.
// ---------------------------------------------------------------------------
__global__ __launch_bounds__(256, 3) void score_mfma(
    const float* __restrict__ z, const ushort_t* __restrict__ Bpack,
    const float* __restrict__ cnorm, int* __restrict__ pidx4)
{
    __shared__ __align__(16) char smraw[40960];
    float* As  = (float*)smraw;             // 64*132*4 = 33792 B (staging)
    float* r1  = (float*)smraw;             // 64*65*4  = 16640 B (reduction)
    float* r2  = (float*)(smraw + 16640);   // 16640 B
    float* t4b = (float*)(smraw + 33280);   // 4096 B

    const int t = threadIdx.x;
    const int wave = t >> 6, lane = t & 63;
    const int set = blockIdx.x;      // 0..127
    const int split = blockIdx.y;    // 0..7
    const int p0 = set * 64;
    const int b  = p0 >> 8;
    const int s0 = p0 & 255;

    for (int idx = t; idx < 64 * 128; idx += 256) {
        int k = idx >> 6, i = idx & 63;
        As[i * 132 + k] = z[(size_t)(b * NE + k) * NS + s0 + i];
    }
    __syncthreads();

    const int am = lane & 15, aq = lane >> 4;
    bf16x8 ah[4][4];
#pragma unroll
    for (int mt = 0; mt < 4; mt++)
#pragma unroll
        for (int ks = 0; ks < 4; ks++) {
            const unsigned* src = (const unsigned*)(As + (mt * 16 + am) * 132 + ks * 32 + aq * 8);
            union { unsigned u[4]; bf16x8 v; } pk;
#pragma unroll
            for (int pr = 0; pr < 4; pr++)
                pk.u[pr] = (src[2 * pr + 1] & 0xFFFF0000u) | (src[2 * pr] >> 16);
            ah[mt][ks] = pk.v;
        }
    __syncthreads();

    const int Gbase = split * 32 + wave * 8;
    float cn[8];
#pragma unroll
    for (int cgi = 0; cgi < 8; cgi++)
        cn[cgi] = cnorm[(Gbase + cgi) * 16 + am];

    float b1v[16], b2v[16];
#pragma unroll
    for (int i = 0; i < 16; i++) { b1v[i] = -1e30f; b2v[i] = -1e30f; }

    bf16x8 bh[4], bhn[4];
#pragma unroll
    for (int ks = 0; ks < 4; ks++)
        bh[ks] = *(const bf16x8*)(Bpack + ((size_t)Gbase * 4 + ks) * 512 + lane * 8);

    for (int cgi = 0; cgi < 8; cgi++) {
        if (cgi < 7) {
#pragma unroll
            for (int ks = 0; ks < 4; ks++)
                bhn[ks] = *(const bf16x8*)(Bpack + ((size_t)(Gbase + cgi + 1) * 4 + ks) * 512 + lane * 8);
        }

        f32x4 acc[4];
#pragma unroll
        for (int mt = 0; mt < 4; mt++) acc[mt] = (f32x4){0.f, 0.f, 0.f, 0.f};
#pragma unroll
        for (int ks = 0; ks < 4; ks++)
#pragma unroll
            for (int mt = 0; mt < 4; mt++)
                acc[mt] = __builtin_amdgcn_mfma_f32_16x16x32_bf16(ah[mt][ks], bh[ks], acc[mt], 0, 0, 0);

#pragma unroll
        for (int mt = 0; mt < 4; mt++)
#pragma unroll
            for (int reg = 0; reg < 4; reg++) {
                const int si = mt * 4 + reg;
                float sc = acc[mt][reg] - cn[cgi];
                float ev = asf((asu(sc) & ~7u) | (unsigned)cgi);
                b2v[si] = fmaxf(b2v[si], fminf(ev, b1v[si]));
                b1v[si] = fmaxf(b1v[si], ev);
            }
#pragma unroll
        for (int ks = 0; ks < 4; ks++) bh[ks] = bhn[ks];
    }

    const int slot = wave * 16 + am;
#pragma unroll
    for (int mt = 0; mt < 4; mt++)
#pragma unroll
        for (int reg = 0; reg < 4; reg++) {
            int px = mt * 16 + aq * 4 + reg;
            r1[slot * 65 + px] = b1v[mt * 4 + reg];
            r2[slot * 65 + px] = b2v[mt * 4 + reg];
        }
    __syncthreads();

    {
        const int px = t >> 2, ch = t & 3;
        float t1 = -1e30f, t2 = -1e30f, t3 = -1e30f, t4 = -1e30f;
        for (int i = 0; i < 16; i++) {
            int sl = ch * 16 + i;
#pragma unroll
            for (int e = 0; e < 2; e++) {
                float raw = e ? r2[sl * 65 + px] : r1[sl * 65 + px];
                unsigned vb = asu(raw);
                float v = asf((vb & ~511u) | ((unsigned)sl << 3) | (vb & 7u));
                t4 = fmaxf(t4, fminf(v, t3));
                t3 = fmaxf(t3, fminf(v, t2));
                t2 = fmaxf(t2, fminf(v, t1));
                t1 = fmaxf(t1, v);
            }
        }
        float* dst = t4b + (px * 4 + ch) * 4;
        dst[0] = t1; dst[1] = t2; dst[2] = t3; dst[3] = t4;
    }
    __syncthreads();

    if (t < 64) {
        float u1 = -1e30f, u2 = -1e30f, u3 = -1e30f, u4 = -1e30f;
        for (int ch = 0; ch < 4; ch++) {
#pragma unroll
            for (int j = 0; j < 4; j++) {
                float v = t4b[(t * 4 + ch) * 4 + j];
                u4 = fmaxf(u4, fminf(v, u3));
                u3 = fmaxf(u3, fminf(v, u2));
                u2 = fmaxf(u2, fminf(v, u1));
                u1 = fmaxf(u1, v);
            }
        }
        const int p = p0 + t;
        float uu[4] = { u1, u2, u3, u4 };
#pragma unroll
        for (int j = 0; j < 4; j++) {
            unsigned bits = asu(uu[j]) & 511u;
            int w = (int)(bits >> 7), res = (int)((bits >> 3) & 15u), cg = (int)(bits & 7u);
            pidx4[((size_t)split * NP + p) * 4 + j] = split * 512 + (w * 8 + cg) * 16 + res;
        }
    }
}

// ---------------------------------------------------------------------------
// K3'' (merged K3+K4, re-parallelized vs round 3):
//   512 threads/block, 16 px/block, 512 blocks.
//   Rescore: 1 candidate/thread (16px x 32cand = 512 threads), 4-way f64
//   partial sums (chain depth 128 -> 32), argmax+tie via 32-lane shfl_xor
//   reduce (rule: higher score, tie -> lower idx == np.argmin). No LDS
//   reduction buffers.
//   Gather: z_q to out_zq + eg[px][k] in LDS.
//   Post_conv: thread = (c = t&255, ph = t>>8); 8 px per thread; post_w row
//   read directly from L2 (no 33KB wtile stage); eg reads are wave-uniform
//   LDS broadcasts; rec written as aligned float4 (2 threads/row -> 64B).
//   LDS 57856 -> ~17KB; launch_bounds (512,4) caps VGPR at 128 -> 2 blk/CU
//   (16 waves) vs round-3's 8.
// ---------------------------------------------------------------------------
__global__ __launch_bounds__(512, 4) void rescore_gather_post2(
    const float* __restrict__ z, const float* __restrict__ emb,
    const int* __restrict__ pidx4, const float* __restrict__ post_w,
    const float* __restrict__ post_b, float* __restrict__ out_zq,
    float* __restrict__ out_rec)
{
    __shared__ __align__(16) float zl[16 * 132];   // 8448 B
    __shared__ __align__(16) float eg[16 * 132];   // 8448 B
    __shared__ int tok[16];                        //   64 B

    const int t  = threadIdx.x;
    const int p0 = blockIdx.x * 16;
    const int b  = p0 >> 8;
    const int s0 = p0 & 255;

    // ---- stage z rows: [px][k], padded stride 132 (16B-aligned rows) ----
    for (int idx = t; idx < 16 * 128; idx += 512) {
        int k = idx >> 4, i = idx & 15;
        zl[i * 132 + k] = z[(size_t)(b * NE + k) * NS + s0 + i];
    }
    __syncthreads();

    // ---- exact f64 rescore: 32 threads/px, 1 candidate each ----
    {
        const int il = t >> 5;   // px local 0..15
        const int cc = t & 31;   // candidate 0..31
        const int p  = p0 + il;
        const int split = cc >> 2, slot = cc & 3;
        const int idx = pidx4[((size_t)split * NP + p) * 4 + slot];
        const float* er = emb + (size_t)idx * NE;
        const float* zr = &zl[il * 132];

        double d0 = 0.0, d1 = 0.0, d2 = 0.0, d3 = 0.0;
        double n0 = 0.0, n1 = 0.0, n2 = 0.0, n3 = 0.0;
#pragma unroll
        for (int k = 0; k < NE; k += 16) {
            float4 e0 = *(const float4*)(er + k + 0);
            float4 e1 = *(const float4*)(er + k + 4);
            float4 e2 = *(const float4*)(er + k + 8);
            float4 e3 = *(const float4*)(er + k + 12);
            float4 z0 = *(const float4*)(zr + k + 0);
            float4 z1 = *(const float4*)(zr + k + 4);
            float4 z2 = *(const float4*)(zr + k + 8);
            float4 z3 = *(const float4*)(zr + k + 12);
            d0 += (double)z0.x * e0.x; d0 += (double)z0.y * e0.y;
            d0 += (double)z0.z * e0.z; d0 += (double)z0.w * e0.w;
            d1 += (double)z1.x * e1.x; d1 += (double)z1.y * e1.y;
            d1 += (double)z1.z * e1.z; d1 += (double)z1.w * e1.w;
            d2 += (double)z2.x * e2.x; d2 += (double)z2.y * e2.y;
            d2 += (double)z2.z * e2.z; d2 += (double)z2.w * e2.w;
            d3 += (double)z3.x * e3.x; d3 += (double)z3.y * e3.y;
            d3 += (double)z3.z * e3.z; d3 += (double)z3.w * e3.w;
            n0 += (double)e0.x * e0.x; n0 += (double)e0.y * e0.y;
            n0 += (double)e0.z * e0.z; n0 += (double)e0.w * e0.w;
            n1 += (double)e1.x * e1.x; n1 += (double)e1.y * e1.y;
            n1 += (double)e1.z * e1.z; n1 += (double)e1.w * e1.w;
            n2 += (double)e2.x * e2.x; n2 += (double)e2.y * e2.y;
            n2 += (double)e2.z * e2.z; n2 += (double)e2.w * e2.w;
            n3 += (double)e3.x * e3.x; n3 += (double)e3.y * e3.y;
            n3 += (double)e3.z * e3.z; n3 += (double)e3.w * e3.w;
        }
        double bs = ((d0 + d1) + (d2 + d3)) - 0.5 * ((n0 + n1) + (n2 + n3));
        int bi = idx;
        // 32-lane argmax reduce (stays within each 32-lane half of the wave)
#pragma unroll
        for (int m = 1; m <= 16; m <<= 1) {
            double osc = __shfl_xor(bs, m);
            int    obi = __shfl_xor(bi, m);
            if (osc > bs || (osc == bs && obi < bi)) { bs = osc; bi = obi; }
        }
        if (cc == 0) tok[il] = bi;
    }
    __syncthreads();

    // ---- gather: write out_zq and stage eg[px][k] ----
    for (int idx = t; idx < NE * 16; idx += 512) {
        int e = idx >> 4, i = idx & 15;
        float v = emb[(size_t)tok[i] * NE + e];
        out_zq[(size_t)(b * NE + e) * NS + s0 + i] = v;
        eg[i * 132 + e] = v;
    }
    __syncthreads();

    // ---- post_conv: thread = (c, ph); 8 px each; w row from L2 ----
    {
        const int c  = t & 255;
        const int ph = t >> 8;          // pixel half: 0 -> px 0..7, 1 -> px 8..15
        const int pb = ph * 8;
        const float* wr = post_w + (size_t)c * NE;

        float a0 = 0.f, a1 = 0.f, a2 = 0.f, a3 = 0.f;
        float a4 = 0.f, a5 = 0.f, a6 = 0.f, a7 = 0.f;
#pragma unroll 4
        for (int k = 0; k < NE; k += 4) {
            float4 w4 = *(const float4*)(wr + k);
            float4 q;
            q = *(const float4*)&eg[(pb + 0) * 132 + k];
            a0 = fmaf(w4.x, q.x, fmaf(w4.y, q.y, fmaf(w4.z, q.z, fmaf(w4.w, q.w, a0))));
            q = *(const float4*)&eg[(pb + 1) * 132 + k];
            a1 = fmaf(w4.x, q.x, fmaf(w4.y, q.y, fmaf(w4.z, q.z, fmaf(w4.w, q.w, a1))));
            q = *(const float4*)&eg[(pb + 2) * 132 + k];
            a2 = fmaf(w4.x, q.x, fmaf(w4.y, q.y, fmaf(w4.z, q.z, fmaf(w4.w, q.w, a2))));
            q = *(const float4*)&eg[(pb + 3) * 132 + k];
            a3 = fmaf(w4.x, q.x, fmaf(w4.y, q.y, fmaf(w4.z, q.z, fmaf(w4.w, q.w, a3))));
            q = *(const float4*)&eg[(pb + 4) * 132 + k];
            a4 = fmaf(w4.x, q.x, fmaf(w4.y, q.y, fmaf(w4.z, q.z, fmaf(w4.w, q.w, a4))));
            q = *(const float4*)&eg[(pb + 5) * 132 + k];
            a5 = fmaf(w4.x, q.x, fmaf(w4.y, q.y, fmaf(w4.z, q.z, fmaf(w4.w, q.w, a5))));
            q = *(const float4*)&eg[(pb + 6) * 132 + k];
            a6 = fmaf(w4.x, q.x, fmaf(w4.y, q.y, fmaf(w4.z, q.z, fmaf(w4.w, q.w, a6))));
            q = *(const float4*)&eg[(pb + 7) * 132 + k];
            a7 = fmaf(w4.x, q.x, fmaf(w4.y, q.y, fmaf(w4.z, q.z, fmaf(w4.w, q.w, a7))));
        }
        const float bias = post_b[c];
        float4 lo = { a0 + bias, a1 + bias, a2 + bias, a3 + bias };
        float4 hi = { a4 + bias, a5 + bias, a6 + bias, a7 + bias };
        float* dst = out_rec + (size_t)(b * NC + c) * NS + s0 + pb;
        *(float4*)(dst + 0) = lo;
        *(float4*)(dst + 4) = hi;
    }
}

// ---------------------------------------------------------------------------
extern "C" void kernel_launch(void* const* d_in, const int* in_sizes, int n_in,
                              void* d_out, int out_size, void* d_ws, size_t ws_size,
                              hipStream_t stream)
{
    const float* z_e    = (const float*)d_in[0];
    const float* pre_w  = (const float*)d_in[1];
    const float* pre_b  = (const float*)d_in[2];
    const float* emb    = (const float*)d_in[3];
    const float* post_w = (const float*)d_in[4];
    const float* post_b = (const float*)d_in[5];

    // d_out: fp32 x 4194304 = (z 1048576 | z_q 1048576 | rec 2097152)
    float* out     = (float*)d_out;
    float* out_z   = out;
    float* out_zq  = out + 1048576;
    float* out_rec = out + 2097152;

    // Scratch: Bpack 1 MB + cnorm 16 KB + pidx4 1 MB. Primary: d_ws;
    // fallback (constant per session): rec-region head (d_ws path has always
    // been taken in this harness, ws_size >= 2 MB).
    const size_t SZ_BPACK = (size_t)256 * 4 * 512 * 2;            // 1 MB
    const size_t SZ_CNORM = (size_t)NV * 4;                       // 16 KB
    const size_t SZ_PIDX4 = (size_t)NSPLIT * NP * 4 * 4;          // 1 MB
    const size_t NEED = SZ_BPACK + SZ_CNORM + SZ_PIDX4;
    char* scr = (ws_size >= NEED) ? (char*)d_ws : (char*)out_rec;
    ushort_t* Bpack = (ushort_t*)scr;
    float*    cnorm = (float*)(scr + SZ_BPACK);
    int*      pidx4 = (int*)(scr + SZ_BPACK + SZ_CNORM);

    pre_conv_pack       <<<dim3(9, 32, 4),    256, 0, stream>>>(z_e, pre_w, pre_b, emb,
                                                                out_z, Bpack, cnorm);
    score_mfma          <<<dim3(128, NSPLIT), 256, 0, stream>>>(out_z, Bpack, cnorm, pidx4);
    rescore_gather_post2<<<dim3(512),         512, 0, stream>>>(out_z, emb, pidx4,
                                                                post_w, post_b,
                                                                out_zq, out_rec);
}

// Round 5
// 144.399 us; speedup vs baseline: 2.3670x; 1.0586x over previous
//
#include <hip/hip_runtime.h>
#include <hip/hip_bf16.h>
#include <cstdint>

// Problem constants
#define NB   32      // batch
#define NC   256     // z channels
#define NE   128     // embed dim
#define NS   256     // H*W pixels per batch
#define NV   4096    // vocab
#define NP   8192    // total pixels
#define NSPLIT 8     // vocab splits (512 codes each)

typedef unsigned short ushort_t;
typedef __attribute__((ext_vector_type(8))) short bf16x8;
typedef __attribute__((ext_vector_type(8))) unsigned short us8;
typedef __attribute__((ext_vector_type(4))) float f32x4;

__device__ __forceinline__ ushort_t f2bf(float f) {
    __hip_bfloat16 h = __float2bfloat16(f);
    ushort_t u; __builtin_memcpy(&u, &h, 2); return u;
}
__device__ __forceinline__ unsigned asu(float f) { unsigned u; __builtin_memcpy(&u,&f,4); return u; }
__device__ __forceinline__ float    asf(unsigned u) { float f; __builtin_memcpy(&f,&u,4); return f; }

// ---------------------------------------------------------------------------
// K0: pack emb hi-bf16 into Bpack (MFMA B-frag order) + cnorm.
// 128 blocks x 32 codes, 8 lanes/code, shfl norm-reduce. (Validated pack
// role from the old pre_conv_pack, grid re-indexed to 1-D.)
// Bpack (ushort units): [(G*4 + ks)*512 + L*8 + j],
//   element = emb[code = G*16 + (L&15)][k = ks*32 + (L>>4)*8 + j]
// ---------------------------------------------------------------------------
__global__ __launch_bounds__(256) void pack_emb(
    const float* __restrict__ emb, ushort_t* __restrict__ Bpack,
    float* __restrict__ cnorm)
{
    const int t = threadIdx.x;
    const int v     = blockIdx.x * 32 + (t >> 3);
    const int chunk = t & 7;
    const float4* rp = (const float4*)(emb + (size_t)v * NE + chunk * 16);
    float4 x0 = rp[0], x1 = rp[1], x2 = rp[2], x3 = rp[3];
    float xs[16] = { x0.x, x0.y, x0.z, x0.w, x1.x, x1.y, x1.z, x1.w,
                     x2.x, x2.y, x2.z, x2.w, x3.x, x3.y, x3.z, x3.w };
    us8 h0, h1;
    float nn = 0.f;
#pragma unroll
    for (int j = 0; j < 8; j++) {
        nn = fmaf(xs[j], xs[j], nn);
        h0[j] = f2bf(xs[j]);
    }
#pragma unroll
    for (int j = 0; j < 8; j++) {
        nn = fmaf(xs[8 + j], xs[8 + j], nn);
        h1[j] = f2bf(xs[8 + j]);
    }
    nn += __shfl_xor(nn, 1);
    nn += __shfl_xor(nn, 2);
    nn += __shfl_xor(nn, 4);
    if (chunk == 0) cnorm[v] = 0.5f * nn;

    const int G  = v >> 4;
    const int ks = chunk >> 1;
    const int q0 = (chunk & 1) * 2;
    const int L0 = (v & 15) | (q0 << 4);
    const int L1 = (v & 15) | ((q0 + 1) << 4);
    *(us8*)(Bpack + ((size_t)G * 4 + ks) * 512 + L0 * 8) = h0;
    *(us8*)(Bpack + ((size_t)G * 4 + ks) * 512 + L1 * 8) = h1;
}

// ---------------------------------------------------------------------------
// K_main: whole pixel pipeline, block = 32 pixels (256 blocks, 512 threads):
//   P1 stage z_e tile (LDS ze[256][36])
//   P2 z-GEMM (f32 VALU): z = pre_w @ ze + pre_b -> zl[32][132] + out_z
//   P3 MFMA scoring vs all 4096 codes, 2 splits in flight (wave-quad each,
//      identical layout/bit-tricks to validated score_mfma, mt 4->2),
//      top-4/split -> cand[8][32][4] in LDS
//   P4 exact f64 rescore of 32 cand/px (2 cand/thread, 4-way partials,
//      16-lane shfl argmax, tie -> lowest idx)
//   P5 gather z_q -> eg (aliases zl) + out_zq
//   P6 post_conv from eg (c = t&255, 2 passes x 8 px) -> out_rec
// LDS arena 62080 B; 1 block/CU (grid-limited), launch_bounds(512,2)
// -> VGPR cap 256, no spill.
// ---------------------------------------------------------------------------
#define ZE_STR  36
#define ZL_STR  132
#define ZE_OFF  0            // 256*36*4 = 36864
#define R1_OFF  0            // 2*64*33*4 = 16896  (aliases ze, dead after P2)
#define R2_OFF  16896        // 16896
#define ZL_OFF  36864        // 32*132*4 = 16896   (eg aliases after P4)
#define T4B_OFF 53760        // 2*32*4*4*4 = 4096
#define CAND_OFF 57856       // 8*32*4*4 = 4096
#define TOK_OFF 61952        // 32*4 = 128
#define SM_SIZE 62080

__global__ __launch_bounds__(512, 2) void vq_main(
    const float* __restrict__ z_e, const float* __restrict__ pre_w,
    const float* __restrict__ pre_b, const float* __restrict__ emb,
    const float* __restrict__ post_w, const float* __restrict__ post_b,
    const ushort_t* __restrict__ Bpack, const float* __restrict__ cnorm,
    float* __restrict__ out_z, float* __restrict__ out_zq,
    float* __restrict__ out_rec)
{
    __shared__ __align__(16) char smraw[SM_SIZE];
    float* ze   = (float*)(smraw + ZE_OFF);
    float* r1   = (float*)(smraw + R1_OFF);
    float* r2   = (float*)(smraw + R2_OFF);
    float* zl   = (float*)(smraw + ZL_OFF);
    float* eg   = (float*)(smraw + ZL_OFF);    // alias, used after P4
    float* t4b  = (float*)(smraw + T4B_OFF);
    int*   cand = (int*)(smraw + CAND_OFF);
    int*   tok  = (int*)(smraw + TOK_OFF);

    const int t  = threadIdx.x;
    const int b  = blockIdx.x >> 3;
    const int s0 = (blockIdx.x & 7) * 32;

    // ================= P1: stage z_e[b, :, s0..s0+32] =================
    for (int idx = t; idx < NC * 32; idx += 512) {
        int c = idx >> 5, i = idx & 31;
        ze[c * ZE_STR + i] = z_e[((size_t)b * NC + c) * NS + s0 + i];
    }
    __syncthreads();

    // ================= P2: z-GEMM (f32) ===============================
    {
        const int pg = t >> 7;       // px group of 8
        const int e  = t & 127;      // embed row
        const float* wr = pre_w + (size_t)e * NC;
        float a0 = 0.f, a1 = 0.f, a2 = 0.f, a3 = 0.f;
        float a4 = 0.f, a5 = 0.f, a6 = 0.f, a7 = 0.f;
#pragma unroll 2
        for (int c = 0; c < NC; c += 4) {
            float4 w4 = *(const float4*)(wr + c);
            float4 za, zb;
            za = *(const float4*)&ze[(c + 0) * ZE_STR + pg * 8];
            zb = *(const float4*)&ze[(c + 0) * ZE_STR + pg * 8 + 4];
            a0 = fmaf(w4.x, za.x, a0); a1 = fmaf(w4.x, za.y, a1);
            a2 = fmaf(w4.x, za.z, a2); a3 = fmaf(w4.x, za.w, a3);
            a4 = fmaf(w4.x, zb.x, a4); a5 = fmaf(w4.x, zb.y, a5);
            a6 = fmaf(w4.x, zb.z, a6); a7 = fmaf(w4.x, zb.w, a7);
            za = *(const float4*)&ze[(c + 1) * ZE_STR + pg * 8];
            zb = *(const float4*)&ze[(c + 1) * ZE_STR + pg * 8 + 4];
            a0 = fmaf(w4.y, za.x, a0); a1 = fmaf(w4.y, za.y, a1);
            a2 = fmaf(w4.y, za.z, a2); a3 = fmaf(w4.y, za.w, a3);
            a4 = fmaf(w4.y, zb.x, a4); a5 = fmaf(w4.y, zb.y, a5);
            a6 = fmaf(w4.y, zb.z, a6); a7 = fmaf(w4.y, zb.w, a7);
            za = *(const float4*)&ze[(c + 2) * ZE_STR + pg * 8];
            zb = *(const float4*)&ze[(c + 2) * ZE_STR + pg * 8 + 4];
            a0 = fmaf(w4.z, za.x, a0); a1 = fmaf(w4.z, za.y, a1);
            a2 = fmaf(w4.z, za.z, a2); a3 = fmaf(w4.z, za.w, a3);
            a4 = fmaf(w4.z, zb.x, a4); a5 = fmaf(w4.z, zb.y, a5);
            a6 = fmaf(w4.z, zb.z, a6); a7 = fmaf(w4.z, zb.w, a7);
            za = *(const float4*)&ze[(c + 3) * ZE_STR + pg * 8];
            zb = *(const float4*)&ze[(c + 3) * ZE_STR + pg * 8 + 4];
            a0 = fmaf(w4.w, za.x, a0); a1 = fmaf(w4.w, za.y, a1);
            a2 = fmaf(w4.w, za.z, a2); a3 = fmaf(w4.w, za.w, a3);
            a4 = fmaf(w4.w, zb.x, a4); a5 = fmaf(w4.w, zb.y, a5);
            a6 = fmaf(w4.w, zb.z, a6); a7 = fmaf(w4.w, zb.w, a7);
        }
        const float bias = pre_b[e];
        a0 += bias; a1 += bias; a2 += bias; a3 += bias;
        a4 += bias; a5 += bias; a6 += bias; a7 += bias;
        // zl[px][e]
        zl[(pg * 8 + 0) * ZL_STR + e] = a0;
        zl[(pg * 8 + 1) * ZL_STR + e] = a1;
        zl[(pg * 8 + 2) * ZL_STR + e] = a2;
        zl[(pg * 8 + 3) * ZL_STR + e] = a3;
        zl[(pg * 8 + 4) * ZL_STR + e] = a4;
        zl[(pg * 8 + 5) * ZL_STR + e] = a5;
        zl[(pg * 8 + 6) * ZL_STR + e] = a6;
        zl[(pg * 8 + 7) * ZL_STR + e] = a7;
        // out_z, 32B contiguous per thread
        float4 lo = { a0, a1, a2, a3 };
        float4 hi = { a4, a5, a6, a7 };
        float* dst = out_z + ((size_t)b * NE + e) * NS + s0 + pg * 8;
        *(float4*)(dst + 0) = lo;
        *(float4*)(dst + 4) = hi;
    }
    __syncthreads();

    // ================= P3: MFMA scoring + top-4/split =================
    const int wave = t >> 6, lane = t & 63;
    const int am = lane & 15, aq = lane >> 4;

    // A-fragments (identical packing to validated score_mfma, mt 4->2)
    bf16x8 ah[2][4];
#pragma unroll
    for (int mt = 0; mt < 2; mt++)
#pragma unroll
        for (int ks = 0; ks < 4; ks++) {
            const unsigned* src = (const unsigned*)(zl + (mt * 16 + am) * ZL_STR + ks * 32 + aq * 8);
            union { unsigned u[4]; bf16x8 v; } pk;
#pragma unroll
            for (int pr = 0; pr < 4; pr++)
                pk.u[pr] = (src[2 * pr + 1] & 0xFFFF0000u) | (src[2 * pr] >> 16);
            ah[mt][ks] = pk.v;
        }

    const int wq = wave >> 2;      // split half within pair
    const int wv = wave & 3;       // plays validated kernel's "wave"

    for (int sp = 0; sp < NSPLIT; sp += 2) {
        const int split = sp + wq;
        const int Gbase = split * 32 + wv * 8;
        float cn[8];
#pragma unroll
        for (int cgi = 0; cgi < 8; cgi++)
            cn[cgi] = cnorm[(Gbase + cgi) * 16 + am];

        float b1v[8], b2v[8];
#pragma unroll
        for (int i = 0; i < 8; i++) { b1v[i] = -1e30f; b2v[i] = -1e30f; }

        bf16x8 bh[4], bhn[4];
#pragma unroll
        for (int ks = 0; ks < 4; ks++)
            bh[ks] = *(const bf16x8*)(Bpack + ((size_t)Gbase * 4 + ks) * 512 + lane * 8);

        for (int cgi = 0; cgi < 8; cgi++) {
            if (cgi < 7) {
#pragma unroll
                for (int ks = 0; ks < 4; ks++)
                    bhn[ks] = *(const bf16x8*)(Bpack + ((size_t)(Gbase + cgi + 1) * 4 + ks) * 512 + lane * 8);
            }
            f32x4 acc[2];
#pragma unroll
            for (int mt = 0; mt < 2; mt++) acc[mt] = (f32x4){0.f, 0.f, 0.f, 0.f};
#pragma unroll
            for (int ks = 0; ks < 4; ks++)
#pragma unroll
                for (int mt = 0; mt < 2; mt++)
                    acc[mt] = __builtin_amdgcn_mfma_f32_16x16x32_bf16(ah[mt][ks], bh[ks], acc[mt], 0, 0, 0);

#pragma unroll
            for (int mt = 0; mt < 2; mt++)
#pragma unroll
                for (int reg = 0; reg < 4; reg++) {
                    const int si = mt * 4 + reg;
                    float sc = acc[mt][reg] - cn[cgi];
                    float ev = asf((asu(sc) & ~7u) | (unsigned)cgi);
                    b2v[si] = fmaxf(b2v[si], fminf(ev, b1v[si]));
                    b1v[si] = fmaxf(b1v[si], ev);
                }
#pragma unroll
            for (int ks = 0; ks < 4; ks++) bh[ks] = bhn[ks];
        }

        const int slot = wv * 16 + am;
#pragma unroll
        for (int mt = 0; mt < 2; mt++)
#pragma unroll
            for (int reg = 0; reg < 4; reg++) {
                int px = mt * 16 + aq * 4 + reg;
                r1[(wq * 64 + slot) * 33 + px] = b1v[mt * 4 + reg];
                r2[(wq * 64 + slot) * 33 + px] = b2v[mt * 4 + reg];
            }
        __syncthreads();

        if (t < 256) {
            const int wq2 = t >> 7, rem = t & 127;
            const int px = rem >> 2, ch = rem & 3;
            float t1 = -1e30f, t2 = -1e30f, t3 = -1e30f, t4 = -1e30f;
            for (int i = 0; i < 16; i++) {
                int sl = ch * 16 + i;
#pragma unroll
                for (int e = 0; e < 2; e++) {
                    float raw = e ? r2[(wq2 * 64 + sl) * 33 + px]
                                  : r1[(wq2 * 64 + sl) * 33 + px];
                    unsigned vb = asu(raw);
                    float v = asf((vb & ~511u) | ((unsigned)sl << 3) | (vb & 7u));
                    t4 = fmaxf(t4, fminf(v, t3));
                    t3 = fmaxf(t3, fminf(v, t2));
                    t2 = fmaxf(t2, fminf(v, t1));
                    t1 = fmaxf(t1, v);
                }
            }
            float* dst = t4b + ((wq2 * 32 + px) * 4 + ch) * 4;
            dst[0] = t1; dst[1] = t2; dst[2] = t3; dst[3] = t4;
        }
        __syncthreads();

        if (t < 64) {
            const int wq2 = t >> 5, px = t & 31;
            float u1 = -1e30f, u2 = -1e30f, u3 = -1e30f, u4 = -1e30f;
            for (int ch = 0; ch < 4; ch++) {
#pragma unroll
                for (int j = 0; j < 4; j++) {
                    float v = t4b[((wq2 * 32 + px) * 4 + ch) * 4 + j];
                    u4 = fmaxf(u4, fminf(v, u3));
                    u3 = fmaxf(u3, fminf(v, u2));
                    u2 = fmaxf(u2, fminf(v, u1));
                    u1 = fmaxf(u1, v);
                }
            }
            const int spw = sp + wq2;
            float uu[4] = { u1, u2, u3, u4 };
#pragma unroll
            for (int j = 0; j < 4; j++) {
                unsigned bits = asu(uu[j]) & 511u;
                int w = (int)(bits >> 7), res = (int)((bits >> 3) & 15u), cg = (int)(bits & 7u);
                cand[(spw * 32 + px) * 4 + j] = spw * 512 + (w * 8 + cg) * 16 + res;
            }
        }
        __syncthreads();
    }

    // ================= P4: exact f64 rescore ==========================
    {
        const int il = t >> 4;   // px 0..31
        const int cc = t & 15;   // candidate pair
        double bs = -1e300; int bi = 0x7fffffff;
        const float* zr = zl + il * ZL_STR;
#pragma unroll
        for (int jj = 0; jj < 2; jj++) {
            int c2 = cc * 2 + jj;
            int split = c2 >> 2, slot = c2 & 3;
            int idx = cand[(split * 32 + il) * 4 + slot];
            const float* er = emb + (size_t)idx * NE;
            double d0 = 0.0, d1 = 0.0, d2 = 0.0, d3 = 0.0;
            double n0 = 0.0, n1 = 0.0, n2 = 0.0, n3 = 0.0;
#pragma unroll
            for (int k = 0; k < NE; k += 16) {
                float4 e0 = *(const float4*)(er + k + 0);
                float4 e1 = *(const float4*)(er + k + 4);
                float4 e2 = *(const float4*)(er + k + 8);
                float4 e3 = *(const float4*)(er + k + 12);
                float4 z0 = *(const float4*)(zr + k + 0);
                float4 z1 = *(const float4*)(zr + k + 4);
                float4 z2 = *(const float4*)(zr + k + 8);
                float4 z3 = *(const float4*)(zr + k + 12);
                d0 += (double)z0.x * e0.x; d0 += (double)z0.y * e0.y;
                d0 += (double)z0.z * e0.z; d0 += (double)z0.w * e0.w;
                d1 += (double)z1.x * e1.x; d1 += (double)z1.y * e1.y;
                d1 += (double)z1.z * e1.z; d1 += (double)z1.w * e1.w;
                d2 += (double)z2.x * e2.x; d2 += (double)z2.y * e2.y;
                d2 += (double)z2.z * e2.z; d2 += (double)z2.w * e2.w;
                d3 += (double)z3.x * e3.x; d3 += (double)z3.y * e3.y;
                d3 += (double)z3.z * e3.z; d3 += (double)z3.w * e3.w;
                n0 += (double)e0.x * e0.x; n0 += (double)e0.y * e0.y;
                n0 += (double)e0.z * e0.z; n0 += (double)e0.w * e0.w;
                n1 += (double)e1.x * e1.x; n1 += (double)e1.y * e1.y;
                n1 += (double)e1.z * e1.z; n1 += (double)e1.w * e1.w;
                n2 += (double)e2.x * e2.x; n2 += (double)e2.y * e2.y;
                n2 += (double)e2.z * e2.z; n2 += (double)e2.w * e2.w;
                n3 += (double)e3.x * e3.x; n3 += (double)e3.y * e3.y;
                n3 += (double)e3.z * e3.z; n3 += (double)e3.w * e3.w;
            }
            double sc = ((d0 + d1) + (d2 + d3)) - 0.5 * ((n0 + n1) + (n2 + n3));
            if (sc > bs || (sc == bs && idx < bi)) { bs = sc; bi = idx; }
        }
#pragma unroll
        for (int m = 1; m <= 8; m <<= 1) {
            double osc = __shfl_xor(bs, m);
            int    obi = __shfl_xor(bi, m);
            if (osc > bs || (osc == bs && obi < bi)) { bs = osc; bi = obi; }
        }
        if (cc == 0) tok[il] = bi;
    }
    __syncthreads();

    // ================= P5: gather z_q -> eg (aliases zl) + out_zq =====
    for (int idx = t; idx < 32 * 32; idx += 512) {      // 2 iters, float4
        int px = idx >> 5, eq = idx & 31;
        float4 v4 = *(const float4*)(emb + (size_t)tok[px] * NE + eq * 4);
        *(float4*)&eg[px * ZL_STR + eq * 4] = v4;
    }
    __syncthreads();
    for (int idx = t; idx < NE * 32; idx += 512) {      // 8 iters, coalesced
        int e = idx >> 5, i = idx & 31;
        out_zq[((size_t)b * NE + e) * NS + s0 + i] = eg[i * ZL_STR + e];
    }
    __syncthreads();

    // ================= P6: post_conv ==================================
    {
        const int c  = t & 255;
        const int ph = t >> 8;
        const float* wr = post_w + (size_t)c * NE;
        const float bias = post_b[c];
#pragma unroll
        for (int pass = 0; pass < 2; pass++) {
            const int pb = pass * 16 + ph * 8;
            float a0 = 0.f, a1 = 0.f, a2 = 0.f, a3 = 0.f;
            float a4 = 0.f, a5 = 0.f, a6 = 0.f, a7 = 0.f;
#pragma unroll 4
            for (int k = 0; k < NE; k += 4) {
                float4 w4 = *(const float4*)(wr + k);
                float4 q;
                q = *(const float4*)&eg[(pb + 0) * ZL_STR + k];
                a0 = fmaf(w4.x, q.x, fmaf(w4.y, q.y, fmaf(w4.z, q.z, fmaf(w4.w, q.w, a0))));
                q = *(const float4*)&eg[(pb + 1) * ZL_STR + k];
                a1 = fmaf(w4.x, q.x, fmaf(w4.y, q.y, fmaf(w4.z, q.z, fmaf(w4.w, q.w, a1))));
                q = *(const float4*)&eg[(pb + 2) * ZL_STR + k];
                a2 = fmaf(w4.x, q.x, fmaf(w4.y, q.y, fmaf(w4.z, q.z, fmaf(w4.w, q.w, a2))));
                q = *(const float4*)&eg[(pb + 3) * ZL_STR + k];
                a3 = fmaf(w4.x, q.x, fmaf(w4.y, q.y, fmaf(w4.z, q.z, fmaf(w4.w, q.w, a3))));
                q = *(const float4*)&eg[(pb + 4) * ZL_STR + k];
                a4 = fmaf(w4.x, q.x, fmaf(w4.y, q.y, fmaf(w4.z, q.z, fmaf(w4.w, q.w, a4))));
                q = *(const float4*)&eg[(pb + 5) * ZL_STR + k];
                a5 = fmaf(w4.x, q.x, fmaf(w4.y, q.y, fmaf(w4.z, q.z, fmaf(w4.w, q.w, a5))));
                q = *(const float4*)&eg[(pb + 6) * ZL_STR + k];
                a6 = fmaf(w4.x, q.x, fmaf(w4.y, q.y, fmaf(w4.z, q.z, fmaf(w4.w, q.w, a6))));
                q = *(const float4*)&eg[(pb + 7) * ZL_STR + k];
                a7 = fmaf(w4.x, q.x, fmaf(w4.y, q.y, fmaf(w4.z, q.z, fmaf(w4.w, q.w, a7))));
            }
            float4 lo = { a0 + bias, a1 + bias, a2 + bias, a3 + bias };
            float4 hi = { a4 + bias, a5 + bias, a6 + bias, a7 + bias };
            float* dst = out_rec + ((size_t)b * NC + c) * NS + s0 + pb;
            *(float4*)(dst + 0) = lo;
            *(float4*)(dst + 4) = hi;
        }
    }
}

// ---------------------------------------------------------------------------
extern "C" void kernel_launch(void* const* d_in, const int* in_sizes, int n_in,
                              void* d_out, int out_size, void* d_ws, size_t ws_size,
                              hipStream_t stream)
{
    const float* z_e    = (const float*)d_in[0];
    const float* pre_w  = (const float*)d_in[1];
    const float* pre_b  = (const float*)d_in[2];
    const float* emb    = (const float*)d_in[3];
    const float* post_w = (const float*)d_in[4];
    const float* post_b = (const float*)d_in[5];

    // d_out: fp32 x 4194304 = (z 1048576 | z_q 1048576 | rec 2097152)
    float* out     = (float*)d_out;
    float* out_z   = out;
    float* out_zq  = out + 1048576;
    float* out_rec = out + 2097152;

    // Scratch: Bpack 1 MB + cnorm 16 KB in d_ws (fallback: rec head; the
    // d_ws path has always been taken in this harness, ws_size >= 2 MB).
    const size_t SZ_BPACK = (size_t)256 * 4 * 512 * 2;            // 1 MB
    const size_t SZ_CNORM = (size_t)NV * 4;                       // 16 KB
    const size_t NEED = SZ_BPACK + SZ_CNORM;
    char* scr = (ws_size >= NEED) ? (char*)d_ws : (char*)out_rec;
    ushort_t* Bpack = (ushort_t*)scr;
    float*    cnorm = (float*)(scr + SZ_BPACK);

    pack_emb<<<dim3(128), 256, 0, stream>>>(emb, Bpack, cnorm);
    vq_main <<<dim3(256), 512, 0, stream>>>(z_e, pre_w, pre_b, emb,
                                            post_w, post_b, Bpack, cnorm,
                                            out_z, out_zq, out_rec);
}